// Round 13
// baseline (337.595 us; speedup 1.0000x reference)
//
#include <hip/hip_runtime.h>
#include <hip/hip_bf16.h>

namespace {

constexpr int NP   = 20000;   // points
constexpr int CD   = 384;     // channels
constexpr int QKVD = 1152;    // 3*C
constexpr int TC   = 47 * 3 * 3 * 64;   // 27072 cart-table elems
constexpr int TS   = 48 * 3 * 3 * 64;   // 27648 sphere-table elems

// merged-prep block ranges
constexpr int PB0 = NP * CD / 4 / 256;          // 7500  cvt qf
constexpr int PB1 = PB0 + (QKVD / 32) * (CD / 32);  // +432 transpose Wqkv
constexpr int PB2 = PB1 + (CD / 32) * (CD / 32);    // +144 transpose Wproj
constexpr int PB3 = PB2 + 27 * 7;                   // +189 tables + sph

// attn geometry (R11 config — best measured: 108.5us)
constexpr int ANB = 240;                        // nodes per block
constexpr int ANY = (NP + ANB - 1) / ANB;       // 84 y-blocks

typedef __attribute__((ext_vector_type(8))) short short8;
typedef __attribute__((ext_vector_type(4))) float f32x4;
typedef __attribute__((ext_vector_type(2))) float f32x2;

// Correctly-rounded fp32 transcendentals via double (match reference libm).
__device__ inline float f32_atan2(float y, float x) {
  return (float)atan2((double)y, (double)x);
}
__device__ inline float f32_log(float x) {
  return (float)log((double)x);
}

__device__ inline float bfl(unsigned u) {   // low bf16 of dword -> f32
  union { unsigned u; float f; } c; c.u = u << 16; return c.f;
}
__device__ inline float bfh(unsigned u) {   // high bf16 of dword -> f32
  union { unsigned u; float f; } c; c.u = u & 0xffff0000u; return c.f;
}
__device__ inline f32x2 up2(unsigned u) {   // dword of 2 bf16 -> packed f32x2
  f32x2 r;
  r.x = bfl(u);
  r.y = bfh(u);
  return r;
}
__device__ inline unsigned short f2bf(float x) {
  __hip_bfloat16 hb = __float2bfloat16(x);
  unsigned short u; __builtin_memcpy(&u, &hb, 2);
  return u;
}

// HW bf16 dot2: d = a.x*b.x + a.y*b.y + c in one VALU op.
#if __has_builtin(__builtin_amdgcn_fdot2_f32_bf16)
#define HAVE_BF16_DOT 1
typedef __attribute__((ext_vector_type(2))) __bf16 bf16x2_t;
__device__ inline float dot2bf(unsigned a, unsigned b, float c) {
  bf16x2_t av, bv;
  __builtin_memcpy(&av, &a, 4);
  __builtin_memcpy(&bv, &b, 4);
  return __builtin_amdgcn_fdot2_f32_bf16(av, bv, c, false);
}
#endif

// XOR-swizzled 16B LDS table access: row*128B rows; XOR row&7 into byte
// bits 4..6 so random-row reads spread across the 8 16B slots (G4 fix).
__device__ inline uint4 tld(const char* t, int row, int bo) {
  return *(const uint4*)(t + row * 128 + (bo ^ ((row & 7) << 4)));
}
__device__ inline void tst(char* t, int row, int bo, uint4 v) {
  *(uint4*)(t + row * 128 + (bo ^ ((row & 7) << 4))) = v;
}

// ---- merged prep: cvt qf, transpose Wqkv/Wproj, table cvt, sph coords ------
__global__ __launch_bounds__(256) void prep_all_k(const float* __restrict__ qf,
                                                  unsigned short* __restrict__ qf_b,
                                                  const float* __restrict__ Wqkv,
                                                  unsigned short* __restrict__ wqkvT,
                                                  const float* __restrict__ Wproj,
                                                  unsigned short* __restrict__ wprojT,
                                                  const float* __restrict__ tq,
                                                  const float* __restrict__ tk,
                                                  const float* __restrict__ tv,
                                                  const float* __restrict__ tqs,
                                                  const float* __restrict__ tks,
                                                  const float* __restrict__ tvs,
                                                  unsigned short* __restrict__ tq_b,
                                                  unsigned short* __restrict__ tk_b,
                                                  unsigned short* __restrict__ tv_b,
                                                  unsigned short* __restrict__ tqs_b,
                                                  unsigned short* __restrict__ tks_b,
                                                  unsigned short* __restrict__ tvs_b,
                                                  const float* __restrict__ xyz,
                                                  float* __restrict__ sph) {
  const int bid = blockIdx.x;
  const int tid = threadIdx.x;
  __shared__ float t[32][33];

  if (bid < PB0) {
    int i = (bid * 256 + tid) * 4;
    float4 v = *(const float4*)(qf + i);
    ushort4 o;
    o.x = f2bf(v.x); o.y = f2bf(v.y); o.z = f2bf(v.z); o.w = f2bf(v.w);
    *(ushort4*)(qf_b + i) = o;
  } else if (bid < PB2) {
    const float* in;
    unsigned short* out;
    int R, Cc, bx, by;
    if (bid < PB1) {
      in = Wqkv; out = wqkvT; R = CD; Cc = QKVD;
      int tt = bid - PB0; bx = tt % (QKVD / 32); by = tt / (QKVD / 32);
    } else {
      in = Wproj; out = wprojT; R = CD; Cc = CD;
      int tt = bid - PB1; bx = tt % (CD / 32); by = tt / (CD / 32);
    }
    const int c0 = bx * 32, r0 = by * 32;
    const int tx = tid & 31, ty = tid >> 5;
    #pragma unroll
    for (int i = 0; i < 32; i += 8)
      t[ty + i][tx] = in[(size_t)(r0 + ty + i) * Cc + (c0 + tx)];
    __syncthreads();
    #pragma unroll
    for (int i = 0; i < 32; i += 8)
      out[(size_t)(c0 + ty + i) * R + (r0 + tx)] = f2bf(t[tx][ty + i]);
  } else {
    const int tt = bid - PB2;
    const int bx = tt % 27, y = tt / 27;
    const int th = bx * 256 + tid;
    if (y < 6) {
      const float* in = (y == 0) ? tq : (y == 1) ? tk : (y == 2) ? tv
                      : (y == 3) ? tqs : (y == 4) ? tks : tvs;
      unsigned short* out = (y == 0) ? tq_b : (y == 1) ? tk_b : (y == 2) ? tv_b
                          : (y == 3) ? tqs_b : (y == 4) ? tks_b : tvs_b;
      const int n = (y < 3) ? TC : TS;   // both divisible by 4
      int i = th * 4;
      if (i < n) {
        float4 v = *(const float4*)(in + i);
        ushort4 o;
        o.x = f2bf(v.x); o.y = f2bf(v.y); o.z = f2bf(v.z); o.w = f2bf(v.w);
        *(ushort4*)(out + i) = o;
      }
    } else {
#pragma clang fp contract(off)
      #pragma unroll
      for (int r = 0; r < 4; ++r) {
        int i = th * 4 + r;
        if (i < NP) {
          const float PIF = 3.14159265358979323846f;
          const float R2D = 57.29577951308232f;
          float x = xyz[i * 3 + 0], yy = xyz[i * 3 + 1], z = xyz[i * 3 + 2];
          float sxy = x * x + yy * yy;
          sph[i * 3 + 0] = (f32_atan2(yy, x) + PIF) * R2D;
          sph[i * 3 + 1] = f32_atan2(sqrtf(sxy), z) * R2D;
          sph[i * 3 + 2] = sqrtf(sxy + z * z);
        }
      }
    }
  }
}

// ---- binning precompute: one thread per (branch, node, edge) ---------------
// Output ebuf[(b*NP + n)*16 + e] = {row0, row1, row2, i1}, row = idx*3+dim.
__global__ __launch_bounds__(256) void bin_k(const float* __restrict__ xyz,
                                             const float* __restrict__ sph,
                                             const int* __restrict__ nb_c,
                                             const int* __restrict__ nb_s,
                                             int4* __restrict__ ebuf) {
#pragma clang fp contract(off)
  const int t = blockIdx.x * 256 + threadIdx.x;
  if (t >= 2 * NP * 16) return;
  const int b   = t / (NP * 16);
  const int rem = t - b * NP * 16;
  const int n   = rem >> 4;
  const int e   = rem & 15;
  int4 o;
  if (b == 0) {
    const int i1 = nb_c[n * 16 + e];
    const float rel[3] = {xyz[n * 3 + 0] - xyz[i1 * 3 + 0],
                          xyz[n * 3 + 1] - xyz[i1 * 3 + 1],
                          xyz[n * 3 + 2] - xyz[i1 * 3 + 2]};
    int r[3];
    #pragma unroll
    for (int dim = 0; dim < 3; ++dim) {
      int idx = (int)floorf(rel[dim] * 4.0f) + 23;
      idx = min(max(idx, 0), 46);
      r[dim] = idx * 3 + dim;
    }
    o.x = r[0]; o.y = r[1]; o.z = r[2]; o.w = i1;
  } else {
    const int i1 = nb_s[n * 16 + e];
    const float d0 = sph[n * 3 + 0] - sph[i1 * 3 + 0];
    const float d1 = sph[n * 3 + 1] - sph[i1 * 3 + 1];
    const float dr = sph[n * 3 + 2] - sph[i1 * 3 + 2];
    int i0a = (int)floorf(d0 / 5.0f) + 24;
    int i1a = (int)floorf(d1 / 5.0f) + 24;
    const float ra = fabsf(dr);
    const float flag = (dr >= 0.0f) ? 1.0f : 0.0f;
    const float tt = (ra + 0.025f) / 0.0125f;
    const float wv = f32_log(tt) / 0.69314718055994531f;
    float fidx = 2.0f * floorf(wv) - 2.0f;
    fidx += ((3.0f * exp2f(floorf(fidx * 0.5f)) - 2.0f) * 0.0125f <= ra) ? 1.0f : 0.0f;
    fidx = fidx * (2.0f * flag - 1.0f) + (flag - 1.0f);
    int i2a = (int)fidx + 24;
    o.x = min(max(i0a, 0), 47) * 3 + 0;
    o.y = min(max(i1a, 0), 47) * 3 + 1;
    o.z = min(max(i2a, 0), 47) * 3 + 2;
    o.w = i1;
  }
  ebuf[t] = o;
}

// ------- bf16 MFMA GEMM, direct-from-global (no LDS, no barriers) -----------
// C[M][Nn] = A[M][384] * BT[Nn][384]^T + bias.
// Rationale (R12): K=384 = 12 K-steps makes the LDS+barrier pipeline
// overhead-bound (2 barriers + vmcnt wait per step never amortize); B panels
// (<=0.9MB) are permanently L2-resident and A streams once -> LDS staging
// buys nothing. Each wave computes an independent 64x64 tile; A/B fragments
// load straight into VGPRs in MFMA layout (same per-lane short8 slices the
// LDS path produced); named ping-pong sets (rule #20); K hardcoded -> full
// unroll folds k-offsets into load immediates. Unguarded fragment loads
// overread <= row 20095 (~74KB) into adjacent workspace (valid memory);
// stores guarded. XCD chunk remap + j2-innermost epilogue kept from R9.
// MODE 0: bf16 out, scale cols < 384 by 0.125. MODE 1: fp32 out.
template <int MODE>
__global__ __launch_bounds__(256) void gemm_direct_k(const short* __restrict__ A,
                                                     const short* __restrict__ BT,
                                                     const float* __restrict__ bias,
                                                     void* __restrict__ Cout,
                                                     int M, int Nn) {
  constexpr int K = 384;
  constexpr int NSTEP = K / 32;   // 12
  const int NT  = Nn >> 7;
  const int nwg = gridDim.x;
  const int q = nwg >> 3, r = nwg & 7;
  const int xcd = blockIdx.x & 7, j = blockIdx.x >> 3;
  const int wg = (xcd < r ? xcd * (q + 1) : r * (q + 1) + (xcd - r) * q) + j;
  const int m0 = (wg / NT) * 128, n0 = (wg % NT) * 128;

  const int tid  = threadIdx.x;
  const int wave = tid >> 6, lane = tid & 63;
  const int wm   = (wave & 1) * 64, wn = (wave >> 1) * 64;
  const int quad = lane >> 4, l16 = lane & 15;

  // per-lane fragment base pointers (MFMA A/B layout: lane = l16 + 16*quad
  // holds row l16, k-cols quad*8..+8 of each 16-row sub-tile)
  const short* ap = A  + (size_t)(m0 + wm + l16) * K + quad * 8;
  const short* bp = BT + (size_t)(n0 + wn + l16) * K + quad * 8;

  f32x4 acc[4][4] = {};
  short8 aA[4], bA[4], aB[4], bB[4];

#define LDFR(as, bs, k0)                                                     \
  do {                                                                       \
    _Pragma("unroll")                                                        \
    for (int i = 0; i < 4; ++i) {                                            \
      as[i] = *(const short8*)(ap + (size_t)i * 16 * K + (k0));              \
      bs[i] = *(const short8*)(bp + (size_t)i * 16 * K + (k0));              \
    }                                                                        \
  } while (0)
#define MM16(as, bs)                                                         \
  do {                                                                       \
    _Pragma("unroll")                                                        \
    for (int i = 0; i < 4; ++i)                                              \
      _Pragma("unroll")                                                      \
      for (int j2 = 0; j2 < 4; ++j2)                                         \
        acc[i][j2] = __builtin_amdgcn_mfma_f32_16x16x32_bf16(                \
            as[i], bs[j2], acc[i][j2], 0, 0, 0);                             \
  } while (0)

  LDFR(aA, bA, 0);
  #pragma unroll
  for (int t = 0; t < NSTEP; t += 2) {
    if (t + 1 < NSTEP) LDFR(aB, bB, (t + 1) * 32);
    MM16(aA, bA);
    if (t + 2 < NSTEP) LDFR(aA, bA, (t + 2) * 32);
    MM16(aB, bB);
  }
#undef LDFR
#undef MM16

  #pragma unroll
  for (int i = 0; i < 4; ++i) {
    #pragma unroll
    for (int r2 = 0; r2 < 4; ++r2) {
      const int gm = m0 + wm + i * 16 + quad * 4 + r2;
      if (gm >= M) continue;
      #pragma unroll
      for (int j2 = 0; j2 < 4; ++j2) {
        const int gn = n0 + wn + j2 * 16 + l16;
        if (gn >= Nn) continue;
        float v = acc[i][j2][r2] + bias[gn];
        if (MODE == 0) {
          if (gn < 384) v *= 0.125f;   // SCALE = 64^-0.5
          ((unsigned short*)Cout)[(size_t)gm * Nn + gn] = f2bf(v);
        } else {
          ((float*)Cout)[(size_t)gm * Nn + gn] = v;
        }
      }
    }
  }
}

// 8-dim partial, packed f32 math (fallback when no HW bf16 dot).
__device__ inline f32x2 dot8_pk(uint4 q, uint4 k, uint4 a0, uint4 a1, uint4 a2,
                                uint4 t0, uint4 t1, uint4 t2, f32x2 acc) {
  const unsigned* qp = &q.x;  const unsigned* kp = &k.x;
  const unsigned* a0p = &a0.x; const unsigned* a1p = &a1.x; const unsigned* a2p = &a2.x;
  const unsigned* t0p = &t0.x; const unsigned* t1p = &t1.x; const unsigned* t2p = &t2.x;
  #pragma unroll
  for (int w2 = 0; w2 < 4; ++w2) {
    f32x2 qf = up2(qp[w2]), kf = up2(kp[w2]);
    f32x2 tqs = up2(a0p[w2]) + up2(a1p[w2]) + up2(a2p[w2]);
    f32x2 tks = up2(t0p[w2]) + up2(t1p[w2]) + up2(t2p[w2]);
    acc += qf * (kf + tqs) + kf * tks;
  }
  return acc;
}

// V-phase accumulate: vc[0..3] += pr * (vv + t0 + t1 + t2), per-dword packed.
__device__ inline void acc4(f32x2* vc, uint4 vv, uint4 t0, uint4 t1, uint4 t2,
                            float pr) {
  f32x2 prv = {pr, pr};
  vc[0] += prv * (up2(vv.x) + up2(t0.x) + up2(t1.x) + up2(t2.x));
  vc[1] += prv * (up2(vv.y) + up2(t0.y) + up2(t1.y) + up2(t2.y));
  vc[2] += prv * (up2(vv.z) + up2(t0.z) + up2(t1.z) + up2(t2.z));
  vc[3] += prv * (up2(vv.w) + up2(t0.w) + up2(t1.w) + up2(t2.w));
}

// -------- fused sparse attention, LDS-staged tables, 16-wave blocks ---------
// R11 config verbatim (best measured: 108.5us). Block = 1024 threads =
// 16 waves, one (branch b, head hh) per x-block; tq/tk/tv head-slices
// (3 x 18KB, XOR-swizzled) staged in LDS once; waves loop over nodes.
__global__ __launch_bounds__(1024, 4) void attn_lds_k(const unsigned short* __restrict__ qkv,
                                                      const int4* __restrict__ ebuf,
                                                      const unsigned short* __restrict__ tq_c,
                                                      const unsigned short* __restrict__ tk_c,
                                                      const unsigned short* __restrict__ tv_c,
                                                      const unsigned short* __restrict__ tq_s,
                                                      const unsigned short* __restrict__ tk_s,
                                                      const unsigned short* __restrict__ tv_s,
                                                      unsigned short* __restrict__ xout) {
  __shared__ char s_tq[144 * 128];
  __shared__ char s_tk[144 * 128];
  __shared__ char s_tv[144 * 128];

  const int bh  = blockIdx.x;      // 0..5
  const int b   = bh / 3;          // branch
  const int hh  = bh % 3;          // head within branch
  const int wid = threadIdx.x >> 6, lane = threadIdx.x & 63;

  const unsigned short* gtq = b ? tq_s : tq_c;
  const unsigned short* gtk = b ? tk_s : tk_c;
  const unsigned short* gtv = b ? tv_s : tv_c;
  const int nrows = b ? 144 : 141;

  // ---- stage table head-slices into LDS (row = r*3+d, 128B rows) ----------
  for (int i = threadIdx.x; i < nrows * 8; i += 1024) {
    const int row = i >> 3, c8 = i & 7;
    const int go = row * 192 + hh * 64 + c8 * 8;   // global elem offset
    tst(s_tq, row, c8 * 16, *(const uint4*)(gtq + go));
    tst(s_tk, row, c8 * 16, *(const uint4*)(gtk + go));
    tst(s_tv, row, c8 * 16, *(const uint4*)(gtv + go));
  }
  __syncthreads();

  const int eg = lane >> 2, g = lane & 3;       // logits mapping
  const int e8 = lane >> 3, c = lane & 7;       // V mapping
  const int node_end = min(blockIdx.y * ANB + ANB, NP);

  for (int node = blockIdx.y * ANB + wid; node < node_end; node += 16) {
    const int4* eb = ebuf + ((size_t)b * NP + node) * 16;

    // per-lane index loads (coalesced 4/8-dup within 256B)
    const int4 E  = eb[eg];                     // logits edge
    const int4 EA = eb[e8];                     // V edges
    const int4 EB = eb[e8 + 8];

    // q + k + v global loads issued up front (v flies under logits+softmax)
    const unsigned short* qp = qkv + (size_t)node * QKVD + b * 192 + hh * 64 + g * 16;
    const uint4 qv0 = *(const uint4*)(qp);
    const uint4 qv1 = *(const uint4*)(qp + 8);
    const unsigned short* kp = qkv + (size_t)E.w * QKVD + 384 + b * 192 + hh * 64 + g * 16;
    const uint4 kv0 = *(const uint4*)(kp);
    const uint4 kv1 = *(const uint4*)(kp + 8);
    const int hc = hh * 64 + c * 8;
    const uint4 vA = *(const uint4*)(qkv + (size_t)EA.w * QKVD + 768 + b * 192 + hc);
    const uint4 vB = *(const uint4*)(qkv + (size_t)EB.w * QKVD + 768 + b * 192 + hc);

    // table operands from LDS (swizzled)
    const int bo = g * 32;
    const uint4 a00 = tld(s_tq, E.x, bo), a01 = tld(s_tq, E.x, bo + 16);
    const uint4 a10 = tld(s_tq, E.y, bo), a11 = tld(s_tq, E.y, bo + 16);
    const uint4 a20 = tld(s_tq, E.z, bo), a21 = tld(s_tq, E.z, bo + 16);
    const uint4 b00 = tld(s_tk, E.x, bo), b01 = tld(s_tk, E.x, bo + 16);
    const uint4 b10 = tld(s_tk, E.y, bo), b11 = tld(s_tk, E.y, bo + 16);
    const uint4 b20 = tld(s_tk, E.z, bo), b21 = tld(s_tk, E.z, bo + 16);

    float acc;
#ifdef HAVE_BF16_DOT
    float aqk = 0.0f, aq0 = 0.0f, aq1 = 0.0f, aq2 = 0.0f;
    float ak0 = 0.0f, ak1 = 0.0f, ak2 = 0.0f;
#define DOT7(qd, kd, a0d, a1d, a2d, b0d, b1d, b2d)                         \
    aqk = dot2bf(qd, kd, aqk);  aq0 = dot2bf(qd, a0d, aq0);                \
    aq1 = dot2bf(qd, a1d, aq1); aq2 = dot2bf(qd, a2d, aq2);                \
    ak0 = dot2bf(kd, b0d, ak0); ak1 = dot2bf(kd, b1d, ak1);                \
    ak2 = dot2bf(kd, b2d, ak2);
    DOT7(qv0.x, kv0.x, a00.x, a10.x, a20.x, b00.x, b10.x, b20.x)
    DOT7(qv0.y, kv0.y, a00.y, a10.y, a20.y, b00.y, b10.y, b20.y)
    DOT7(qv0.z, kv0.z, a00.z, a10.z, a20.z, b00.z, b10.z, b20.z)
    DOT7(qv0.w, kv0.w, a00.w, a10.w, a20.w, b00.w, b10.w, b20.w)
    DOT7(qv1.x, kv1.x, a01.x, a11.x, a21.x, b01.x, b11.x, b21.x)
    DOT7(qv1.y, kv1.y, a01.y, a11.y, a21.y, b01.y, b11.y, b21.y)
    DOT7(qv1.z, kv1.z, a01.z, a11.z, a21.z, b01.z, b11.z, b21.z)
    DOT7(qv1.w, kv1.w, a01.w, a11.w, a21.w, b01.w, b11.w, b21.w)
#undef DOT7
    acc = ((aqk + aq0) + (aq1 + aq2)) + ((ak0 + ak1) + ak2);
#else
    f32x2 acc2 = {0.0f, 0.0f};
    acc2 = dot8_pk(qv0, kv0, a00, a10, a20, b00, b10, b20, acc2);
    acc2 = dot8_pk(qv1, kv1, a01, a11, a21, b01, b11, b21, acc2);
    acc = acc2.x + acc2.y;
#endif
    // edge-local reduce over 4 dim-groups (lane bits 0..1)
    acc += __shfl_xor(acc, 1);
    acc += __shfl_xor(acc, 2);

    // in-wave softmax over 16 edges (lane bits 2..5)
    float m = acc;
    #pragma unroll
    for (int off = 4; off <= 32; off <<= 1) m = fmaxf(m, __shfl_xor(m, off));
    float ex = __expf(acc - m);
    float s = ex;
    #pragma unroll
    for (int off = 4; off <= 32; off <<= 1) s += __shfl_xor(s, off);
    const float p = ex / s;

    // V phase: p for edges e8 / e8+8 via shuffle from lane 4*e
    const float pA = __shfl(p, e8 << 2);
    const float pB = __shfl(p, (e8 + 8) << 2);
    const int vbo = c * 16;
    const uint4 tA0 = tld(s_tv, EA.x, vbo);
    const uint4 tA1 = tld(s_tv, EA.y, vbo);
    const uint4 tA2 = tld(s_tv, EA.z, vbo);
    const uint4 tB0 = tld(s_tv, EB.x, vbo);
    const uint4 tB1 = tld(s_tv, EB.y, vbo);
    const uint4 tB2 = tld(s_tv, EB.z, vbo);

    f32x2 vc[4] = {{0.f, 0.f}, {0.f, 0.f}, {0.f, 0.f}, {0.f, 0.f}};
    acc4(vc, vA, tA0, tA1, tA2, pA);
    acc4(vc, vB, tB0, tB1, tB2, pB);

    #pragma unroll
    for (int q4 = 0; q4 < 4; ++q4) {
      #pragma unroll
      for (int off = 8; off <= 32; off <<= 1) {
        vc[q4].x += __shfl_xor(vc[q4].x, off);
        vc[q4].y += __shfl_xor(vc[q4].y, off);
      }
    }
    if (e8 == 0) {
      uint4 o;
      o.x = ((unsigned)f2bf(vc[0].y) << 16) | (unsigned)f2bf(vc[0].x);
      o.y = ((unsigned)f2bf(vc[1].y) << 16) | (unsigned)f2bf(vc[1].x);
      o.z = ((unsigned)f2bf(vc[2].y) << 16) | (unsigned)f2bf(vc[2].x);
      o.w = ((unsigned)f2bf(vc[3].y) << 16) | (unsigned)f2bf(vc[3].x);
      *(uint4*)(xout + (size_t)node * CD + (b * 3 + hh) * 64 + c * 8) = o;
    }
  }
}

}  // namespace

extern "C" void kernel_launch(void* const* d_in, const int* in_sizes, int n_in,
                              void* d_out, int out_size, void* d_ws, size_t ws_size,
                              hipStream_t stream) {
  const float* qf    = (const float*)d_in[0];
  const float* xyz   = (const float*)d_in[1];
  const int*   i1c   = (const int*)d_in[3];   // index_1
  const int*   i1s   = (const int*)d_in[5];   // index_1_sphere
  const float* Wqkv  = (const float*)d_in[6];
  const float* bqkv  = (const float*)d_in[7];
  const float* Wproj = (const float*)d_in[8];
  const float* bproj = (const float*)d_in[9];
  const float* tq    = (const float*)d_in[10];
  const float* tk    = (const float*)d_in[11];
  const float* tv    = (const float*)d_in[12];
  const float* tqs   = (const float*)d_in[13];
  const float* tks   = (const float*)d_in[14];
  const float* tvs   = (const float*)d_in[15];

  char* w = (char*)d_ws;
  unsigned short* qf_b   = (unsigned short*)w; w += (size_t)NP * CD * 2;    // 15.36 MB
  unsigned short* wqkvT  = (unsigned short*)w; w += (size_t)QKVD * CD * 2;  // 0.88 MB
  unsigned short* wprojT = (unsigned short*)w; w += (size_t)CD * CD * 2;    // 0.29 MB
  unsigned short* qkv_b  = (unsigned short*)w; w += (size_t)NP * QKVD * 2;  // 46.08 MB
  unsigned short* x_b    = (unsigned short*)w; w += (size_t)NP * CD * 2;    // 15.36 MB
  float*          sph    = (float*)w;          w += (size_t)NP * 3 * 4;     // 0.24 MB
  unsigned short* tq_b   = (unsigned short*)w; w += (size_t)TC * 2;
  unsigned short* tk_b   = (unsigned short*)w; w += (size_t)TC * 2;
  unsigned short* tv_b   = (unsigned short*)w; w += (size_t)TC * 2;
  unsigned short* tqs_b  = (unsigned short*)w; w += (size_t)TS * 2;
  unsigned short* tks_b  = (unsigned short*)w; w += (size_t)TS * 2;
  unsigned short* tvs_b  = (unsigned short*)w; w += (size_t)TS * 2;
  int4*           ebuf   = (int4*)w;           // 10.24 MB

  prep_all_k<<<PB3, 256, 0, stream>>>(qf, qf_b, Wqkv, wqkvT, Wproj, wprojT,
                                      tq, tk, tv, tqs, tks, tvs,
                                      tq_b, tk_b, tv_b, tqs_b, tks_b, tvs_b,
                                      xyz, sph);

  bin_k<<<(2 * NP * 16 + 255) / 256, 256, 0, stream>>>(xyz, sph, i1c, i1s, ebuf);

  gemm_direct_k<0><<<((NP + 127) / 128) * (QKVD / 128), 256, 0, stream>>>(
      (const short*)qf_b, (const short*)wqkvT, bqkv, qkv_b, NP, QKVD);

  attn_lds_k<<<dim3(6, ANY), 1024, 0, stream>>>(qkv_b, ebuf,
                                                tq_b, tk_b, tv_b,
                                                tqs_b, tks_b, tvs_b, x_b);

  gemm_direct_k<1><<<((NP + 127) / 128) * (CD / 128), 256, 0, stream>>>(
      (const short*)x_b, (const short*)wprojT, bproj, d_out, NP, CD);
}

// Round 14
// 284.465 us; speedup vs baseline: 1.1868x; 1.1868x over previous
//
#include <hip/hip_runtime.h>
#include <hip/hip_bf16.h>

namespace {

constexpr int NP   = 20000;   // points
constexpr int CD   = 384;     // channels
constexpr int QKVD = 1152;    // 3*C
constexpr int TC   = 47 * 3 * 3 * 64;   // 27072 cart-table elems
constexpr int TS   = 48 * 3 * 3 * 64;   // 27648 sphere-table elems

// merged-prep block ranges
constexpr int PB0 = NP * CD / 4 / 256;          // 7500  cvt qf
constexpr int PB1 = PB0 + (QKVD / 32) * (CD / 32);  // +432 transpose Wqkv
constexpr int PB2 = PB1 + (CD / 32) * (CD / 32);    // +144 transpose Wproj
constexpr int PB3 = PB2 + 27 * 7;                   // +189 tables + sph

// attn geometry (R11 config — best measured: 108.5us fused)
constexpr int ANB = 240;                        // nodes per block
constexpr int ANY = (NP + ANB - 1) / ANB;       // 84 y-blocks

typedef __attribute__((ext_vector_type(8))) short short8;
typedef __attribute__((ext_vector_type(4))) float f32x4;
typedef __attribute__((ext_vector_type(2))) float f32x2;

// Correctly-rounded fp32 transcendentals via double (match reference libm).
__device__ inline float f32_atan2(float y, float x) {
  return (float)atan2((double)y, (double)x);
}
__device__ inline float f32_log(float x) {
  return (float)log((double)x);
}

__device__ inline float bfl(unsigned u) {   // low bf16 of dword -> f32
  union { unsigned u; float f; } c; c.u = u << 16; return c.f;
}
__device__ inline float bfh(unsigned u) {   // high bf16 of dword -> f32
  union { unsigned u; float f; } c; c.u = u & 0xffff0000u; return c.f;
}
__device__ inline f32x2 up2(unsigned u) {   // dword of 2 bf16 -> packed f32x2
  f32x2 r;
  r.x = bfl(u);
  r.y = bfh(u);
  return r;
}
__device__ inline unsigned short f2bf(float x) {
  __hip_bfloat16 hb = __float2bfloat16(x);
  unsigned short u; __builtin_memcpy(&u, &hb, 2);
  return u;
}

// HW bf16 dot2: d = a.x*b.x + a.y*b.y + c in one VALU op.
#if __has_builtin(__builtin_amdgcn_fdot2_f32_bf16)
#define HAVE_BF16_DOT 1
typedef __attribute__((ext_vector_type(2))) __bf16 bf16x2_t;
__device__ inline float dot2bf(unsigned a, unsigned b, float c) {
  bf16x2_t av, bv;
  __builtin_memcpy(&av, &a, 4);
  __builtin_memcpy(&bv, &b, 4);
  return __builtin_amdgcn_fdot2_f32_bf16(av, bv, c, false);
}
#endif

// async 16B global -> LDS (global_load_lds_dwordx4). LDS dest must be the
// wave-uniform base; HW adds lane*16.
__device__ inline void async16(const void* g, void* l) {
  __builtin_amdgcn_global_load_lds(
      (const __attribute__((address_space(1))) unsigned int*)g,
      (__attribute__((address_space(3))) unsigned int*)l,
      16, 0, 0);
}

// XOR-swizzled 16B LDS table access: row*128B rows; XOR row&7 into byte
// bits 4..6 so random-row reads spread across the 8 16B slots (G4 fix).
__device__ inline uint4 tld(const char* t, int row, int bo) {
  return *(const uint4*)(t + row * 128 + (bo ^ ((row & 7) << 4)));
}
__device__ inline void tst(char* t, int row, int bo, uint4 v) {
  *(uint4*)(t + row * 128 + (bo ^ ((row & 7) << 4))) = v;
}

// ---- merged prep: cvt qf, transpose Wqkv/Wproj, table cvt, sph coords ------
__global__ __launch_bounds__(256) void prep_all_k(const float* __restrict__ qf,
                                                  unsigned short* __restrict__ qf_b,
                                                  const float* __restrict__ Wqkv,
                                                  unsigned short* __restrict__ wqkvT,
                                                  const float* __restrict__ Wproj,
                                                  unsigned short* __restrict__ wprojT,
                                                  const float* __restrict__ tq,
                                                  const float* __restrict__ tk,
                                                  const float* __restrict__ tv,
                                                  const float* __restrict__ tqs,
                                                  const float* __restrict__ tks,
                                                  const float* __restrict__ tvs,
                                                  unsigned short* __restrict__ tq_b,
                                                  unsigned short* __restrict__ tk_b,
                                                  unsigned short* __restrict__ tv_b,
                                                  unsigned short* __restrict__ tqs_b,
                                                  unsigned short* __restrict__ tks_b,
                                                  unsigned short* __restrict__ tvs_b,
                                                  const float* __restrict__ xyz,
                                                  float* __restrict__ sph) {
  const int bid = blockIdx.x;
  const int tid = threadIdx.x;
  __shared__ float t[32][33];

  if (bid < PB0) {
    int i = (bid * 256 + tid) * 4;
    float4 v = *(const float4*)(qf + i);
    ushort4 o;
    o.x = f2bf(v.x); o.y = f2bf(v.y); o.z = f2bf(v.z); o.w = f2bf(v.w);
    *(ushort4*)(qf_b + i) = o;
  } else if (bid < PB2) {
    const float* in;
    unsigned short* out;
    int R, Cc, bx, by;
    if (bid < PB1) {
      in = Wqkv; out = wqkvT; R = CD; Cc = QKVD;
      int tt = bid - PB0; bx = tt % (QKVD / 32); by = tt / (QKVD / 32);
    } else {
      in = Wproj; out = wprojT; R = CD; Cc = CD;
      int tt = bid - PB1; bx = tt % (CD / 32); by = tt / (CD / 32);
    }
    const int c0 = bx * 32, r0 = by * 32;
    const int tx = tid & 31, ty = tid >> 5;
    #pragma unroll
    for (int i = 0; i < 32; i += 8)
      t[ty + i][tx] = in[(size_t)(r0 + ty + i) * Cc + (c0 + tx)];
    __syncthreads();
    #pragma unroll
    for (int i = 0; i < 32; i += 8)
      out[(size_t)(c0 + ty + i) * R + (r0 + tx)] = f2bf(t[tx][ty + i]);
  } else {
    const int tt = bid - PB2;
    const int bx = tt % 27, y = tt / 27;
    const int th = bx * 256 + tid;
    if (y < 6) {
      const float* in = (y == 0) ? tq : (y == 1) ? tk : (y == 2) ? tv
                      : (y == 3) ? tqs : (y == 4) ? tks : tvs;
      unsigned short* out = (y == 0) ? tq_b : (y == 1) ? tk_b : (y == 2) ? tv_b
                          : (y == 3) ? tqs_b : (y == 4) ? tks_b : tvs_b;
      const int n = (y < 3) ? TC : TS;   // both divisible by 4
      int i = th * 4;
      if (i < n) {
        float4 v = *(const float4*)(in + i);
        ushort4 o;
        o.x = f2bf(v.x); o.y = f2bf(v.y); o.z = f2bf(v.z); o.w = f2bf(v.w);
        *(ushort4*)(out + i) = o;
      }
    } else {
#pragma clang fp contract(off)
      #pragma unroll
      for (int r = 0; r < 4; ++r) {
        int i = th * 4 + r;
        if (i < NP) {
          const float PIF = 3.14159265358979323846f;
          const float R2D = 57.29577951308232f;
          float x = xyz[i * 3 + 0], yy = xyz[i * 3 + 1], z = xyz[i * 3 + 2];
          float sxy = x * x + yy * yy;
          sph[i * 3 + 0] = (f32_atan2(yy, x) + PIF) * R2D;
          sph[i * 3 + 1] = f32_atan2(sqrtf(sxy), z) * R2D;
          sph[i * 3 + 2] = sqrtf(sxy + z * z);
        }
      }
    }
  }
}

// ---- binning precompute: one thread per (branch, node, edge) ---------------
// Output ebuf[(b*NP + n)*16 + e] = {row0, row1, row2, i1}, row = idx*3+dim.
__global__ __launch_bounds__(256) void bin_k(const float* __restrict__ xyz,
                                             const float* __restrict__ sph,
                                             const int* __restrict__ nb_c,
                                             const int* __restrict__ nb_s,
                                             int4* __restrict__ ebuf) {
#pragma clang fp contract(off)
  const int t = blockIdx.x * 256 + threadIdx.x;
  if (t >= 2 * NP * 16) return;
  const int b   = t / (NP * 16);
  const int rem = t - b * NP * 16;
  const int n   = rem >> 4;
  const int e   = rem & 15;
  int4 o;
  if (b == 0) {
    const int i1 = nb_c[n * 16 + e];
    const float rel[3] = {xyz[n * 3 + 0] - xyz[i1 * 3 + 0],
                          xyz[n * 3 + 1] - xyz[i1 * 3 + 1],
                          xyz[n * 3 + 2] - xyz[i1 * 3 + 2]};
    int r[3];
    #pragma unroll
    for (int dim = 0; dim < 3; ++dim) {
      int idx = (int)floorf(rel[dim] * 4.0f) + 23;
      idx = min(max(idx, 0), 46);
      r[dim] = idx * 3 + dim;
    }
    o.x = r[0]; o.y = r[1]; o.z = r[2]; o.w = i1;
  } else {
    const int i1 = nb_s[n * 16 + e];
    const float d0 = sph[n * 3 + 0] - sph[i1 * 3 + 0];
    const float d1 = sph[n * 3 + 1] - sph[i1 * 3 + 1];
    const float dr = sph[n * 3 + 2] - sph[i1 * 3 + 2];
    int i0a = (int)floorf(d0 / 5.0f) + 24;
    int i1a = (int)floorf(d1 / 5.0f) + 24;
    const float ra = fabsf(dr);
    const float flag = (dr >= 0.0f) ? 1.0f : 0.0f;
    const float tt = (ra + 0.025f) / 0.0125f;
    const float wv = f32_log(tt) / 0.69314718055994531f;
    float fidx = 2.0f * floorf(wv) - 2.0f;
    fidx += ((3.0f * exp2f(floorf(fidx * 0.5f)) - 2.0f) * 0.0125f <= ra) ? 1.0f : 0.0f;
    fidx = fidx * (2.0f * flag - 1.0f) + (flag - 1.0f);
    int i2a = (int)fidx + 24;
    o.x = min(max(i0a, 0), 47) * 3 + 0;
    o.y = min(max(i1a, 0), 47) * 3 + 1;
    o.z = min(max(i2a, 0), 47) * 3 + 2;
    o.w = i1;
  }
  ebuf[t] = o;
}

// ------- bf16 MFMA GEMM: 3-buffer depth-2 prefetch + XCD chunk remap --------
// (R9 version — best measured. R13's direct-from-global variant was 57us
// SLOWER: register-fragment sets cost occupancy and depth-1 ping-pong
// round-trips L2 latency per K-step; LDS broadcast + global_load_lds wins.)
// Ledger (per wave, 4 loads/stage): top of iter t outstanding = {t,t+1} = 8;
// vmcnt(4) drains exactly tile t; buffers t%3 disjoint for {t,t+1,t+2};
// buf (t+2)%3 last read before barrier2(t-1).
// MODE 0: bf16 out, scale cols < 384 by 0.125. MODE 1: fp32 out.
template <int MODE>
__global__ __launch_bounds__(256) void gemm_async_k(const short* __restrict__ A,
                                                    const short* __restrict__ BT,
                                                    const float* __restrict__ bias,
                                                    void* __restrict__ Cout,
                                                    int M, int Nn, int K) {
  __shared__ short As[3][128][32];
  __shared__ short Bs[3][128][32];
  const int tid  = threadIdx.x;

  // bijective XCD chunk remap (m204): xcd = orig%8 gets contiguous wg range.
  const int NT  = Nn >> 7;
  const int nwg = gridDim.x;
  const int q = nwg >> 3, r = nwg & 7;
  const int xcd = blockIdx.x & 7, j = blockIdx.x >> 3;
  const int wg = (xcd < r ? xcd * (q + 1) : r * (q + 1) + (xcd - r) * q) + j;
  const int m0 = (wg / NT) * 128, n0 = (wg % NT) * 128;

  const int wave = tid >> 6, lane = tid & 63;
  const int wm   = (wave & 1) * 64, wn = (wave >> 1) * 64;
  const int quad = lane >> 4, l16 = lane & 15;
  const int srow = lane >> 2;
  const int scol = (lane & 3) * 8;   // shorts

  f32x4 acc[4][4] = {};

  auto stage = [&](int buf, int k0) {
    #pragma unroll
    for (int c = 0; c < 2; ++c) {
      const int base = (wave + c * 4) * 16;      // wave-uniform: 0..112
      async16(A + (size_t)(m0 + base + srow) * K + k0 + scol, &As[buf][base][0]);
      async16(BT + (size_t)(n0 + base + srow) * K + k0 + scol, &Bs[buf][base][0]);
    }
  };

  const int nt = K >> 5;          // K/32 tiles (>=2 for both call sites)
  stage(0, 0);
  stage(1, 32);
  for (int t = 0; t < nt; ++t) {
    const int cur = t % 3;
    if (t + 1 < nt) {
      asm volatile("s_waitcnt vmcnt(4)" ::: "memory");   // tile t landed
    } else {
      asm volatile("s_waitcnt vmcnt(0)" ::: "memory");
    }
    __builtin_amdgcn_s_barrier();   // all waves: tile t staged
    short8 af[4], bg[4];
    #pragma unroll
    for (int i = 0; i < 4; ++i) af[i] = *(const short8*)&As[cur][wm + i * 16 + l16][quad * 8];
    #pragma unroll
    for (int j2 = 0; j2 < 4; ++j2) bg[j2] = *(const short8*)&Bs[cur][wn + j2 * 16 + l16][quad * 8];
    #pragma unroll
    for (int i = 0; i < 4; ++i)
      #pragma unroll
      for (int j2 = 0; j2 < 4; ++j2)
        acc[i][j2] = __builtin_amdgcn_mfma_f32_16x16x32_bf16(af[i], bg[j2], acc[i][j2], 0, 0, 0);
    __builtin_amdgcn_s_barrier();   // all reads of tile t done before re-stage
    if (t + 2 < nt) stage((t + 2) % 3, (t + 2) * 32);
  }

  #pragma unroll
  for (int i = 0; i < 4; ++i) {
    #pragma unroll
    for (int r2 = 0; r2 < 4; ++r2) {
      const int gm = m0 + wm + i * 16 + quad * 4 + r2;
      if (gm >= M) continue;
      #pragma unroll
      for (int j2 = 0; j2 < 4; ++j2) {
        const int gn = n0 + wn + j2 * 16 + l16;
        if (gn >= Nn) continue;
        float v = acc[i][j2][r2] + bias[gn];
        if (MODE == 0) {
          if (gn < 384) v *= 0.125f;   // SCALE = 64^-0.5
          ((unsigned short*)Cout)[(size_t)gm * Nn + gn] = f2bf(v);
        } else {
          ((float*)Cout)[(size_t)gm * Nn + gn] = v;
        }
      }
    }
  }
}

// 8-dim partial, packed f32 math (fallback when no HW bf16 dot).
__device__ inline f32x2 dot8_pk(uint4 q, uint4 k, uint4 a0, uint4 a1, uint4 a2,
                                uint4 t0, uint4 t1, uint4 t2, f32x2 acc) {
  const unsigned* qp = &q.x;  const unsigned* kp = &k.x;
  const unsigned* a0p = &a0.x; const unsigned* a1p = &a1.x; const unsigned* a2p = &a2.x;
  const unsigned* t0p = &t0.x; const unsigned* t1p = &t1.x; const unsigned* t2p = &t2.x;
  #pragma unroll
  for (int w2 = 0; w2 < 4; ++w2) {
    f32x2 qf = up2(qp[w2]), kf = up2(kp[w2]);
    f32x2 tqs = up2(a0p[w2]) + up2(a1p[w2]) + up2(a2p[w2]);
    f32x2 tks = up2(t0p[w2]) + up2(t1p[w2]) + up2(t2p[w2]);
    acc += qf * (kf + tqs) + kf * tks;
  }
  return acc;
}

// V-phase accumulate: vc[0..3] += pr * (vv + t0 + t1 + t2), per-dword packed.
__device__ inline void acc4(f32x2* vc, uint4 vv, uint4 t0, uint4 t1, uint4 t2,
                            float pr) {
  f32x2 prv = {pr, pr};
  vc[0] += prv * (up2(vv.x) + up2(t0.x) + up2(t1.x) + up2(t2.x));
  vc[1] += prv * (up2(vv.y) + up2(t0.y) + up2(t1.y) + up2(t2.y));
  vc[2] += prv * (up2(vv.z) + up2(t0.z) + up2(t1.z) + up2(t2.z));
  vc[3] += prv * (up2(vv.w) + up2(t0.w) + up2(t1.w) + up2(t2.w));
}

// -------- fused sparse attention, LDS-staged tables, 16-wave blocks ---------
// R11 body; launched as TWO dispatches (bh 0-2 / 3-5). With 1024-thread
// blocks each half = 252 blocks ~ 1/CU = 16 waves/CU — the same effective
// occupancy the fused launch measured (35.6% ~ 11 waves/CU), so the split is
// ~free (unlike R10's 512-thread halves at 8 waves/CU). Purpose: any other
// dispatch > ~55us (i.e. gemm0 if it dominates the 170us remainder) now
// surfaces in rocprof top-5 with full counters.
__global__ __launch_bounds__(1024, 4) void attn_lds_k(const unsigned short* __restrict__ qkv,
                                                      const int4* __restrict__ ebuf,
                                                      const unsigned short* __restrict__ tq_c,
                                                      const unsigned short* __restrict__ tk_c,
                                                      const unsigned short* __restrict__ tv_c,
                                                      const unsigned short* __restrict__ tq_s,
                                                      const unsigned short* __restrict__ tk_s,
                                                      const unsigned short* __restrict__ tv_s,
                                                      unsigned short* __restrict__ xout,
                                                      int bh_base) {
  __shared__ char s_tq[144 * 128];
  __shared__ char s_tk[144 * 128];
  __shared__ char s_tv[144 * 128];

  const int bh  = bh_base + blockIdx.x;   // 0..5
  const int b   = bh / 3;          // branch
  const int hh  = bh % 3;          // head within branch
  const int wid = threadIdx.x >> 6, lane = threadIdx.x & 63;

  const unsigned short* gtq = b ? tq_s : tq_c;
  const unsigned short* gtk = b ? tk_s : tk_c;
  const unsigned short* gtv = b ? tv_s : tv_c;
  const int nrows = b ? 144 : 141;

  // ---- stage table head-slices into LDS (row = r*3+d, 128B rows) ----------
  for (int i = threadIdx.x; i < nrows * 8; i += 1024) {
    const int row = i >> 3, c8 = i & 7;
    const int go = row * 192 + hh * 64 + c8 * 8;   // global elem offset
    tst(s_tq, row, c8 * 16, *(const uint4*)(gtq + go));
    tst(s_tk, row, c8 * 16, *(const uint4*)(gtk + go));
    tst(s_tv, row, c8 * 16, *(const uint4*)(gtv + go));
  }
  __syncthreads();

  const int eg = lane >> 2, g = lane & 3;       // logits mapping
  const int e8 = lane >> 3, c = lane & 7;       // V mapping
  const int node_end = min(blockIdx.y * ANB + ANB, NP);

  for (int node = blockIdx.y * ANB + wid; node < node_end; node += 16) {
    const int4* eb = ebuf + ((size_t)b * NP + node) * 16;

    // per-lane index loads (coalesced 4/8-dup within 256B)
    const int4 E  = eb[eg];                     // logits edge
    const int4 EA = eb[e8];                     // V edges
    const int4 EB = eb[e8 + 8];

    // q + k + v global loads issued up front (v flies under logits+softmax)
    const unsigned short* qp = qkv + (size_t)node * QKVD + b * 192 + hh * 64 + g * 16;
    const uint4 qv0 = *(const uint4*)(qp);
    const uint4 qv1 = *(const uint4*)(qp + 8);
    const unsigned short* kp = qkv + (size_t)E.w * QKVD + 384 + b * 192 + hh * 64 + g * 16;
    const uint4 kv0 = *(const uint4*)(kp);
    const uint4 kv1 = *(const uint4*)(kp + 8);
    const int hc = hh * 64 + c * 8;
    const uint4 vA = *(const uint4*)(qkv + (size_t)EA.w * QKVD + 768 + b * 192 + hc);
    const uint4 vB = *(const uint4*)(qkv + (size_t)EB.w * QKVD + 768 + b * 192 + hc);

    // table operands from LDS (swizzled)
    const int bo = g * 32;
    const uint4 a00 = tld(s_tq, E.x, bo), a01 = tld(s_tq, E.x, bo + 16);
    const uint4 a10 = tld(s_tq, E.y, bo), a11 = tld(s_tq, E.y, bo + 16);
    const uint4 a20 = tld(s_tq, E.z, bo), a21 = tld(s_tq, E.z, bo + 16);
    const uint4 b00 = tld(s_tk, E.x, bo), b01 = tld(s_tk, E.x, bo + 16);
    const uint4 b10 = tld(s_tk, E.y, bo), b11 = tld(s_tk, E.y, bo + 16);
    const uint4 b20 = tld(s_tk, E.z, bo), b21 = tld(s_tk, E.z, bo + 16);

    float acc;
#ifdef HAVE_BF16_DOT
    float aqk = 0.0f, aq0 = 0.0f, aq1 = 0.0f, aq2 = 0.0f;
    float ak0 = 0.0f, ak1 = 0.0f, ak2 = 0.0f;
#define DOT7(qd, kd, a0d, a1d, a2d, b0d, b1d, b2d)                         \
    aqk = dot2bf(qd, kd, aqk);  aq0 = dot2bf(qd, a0d, aq0);                \
    aq1 = dot2bf(qd, a1d, aq1); aq2 = dot2bf(qd, a2d, aq2);                \
    ak0 = dot2bf(kd, b0d, ak0); ak1 = dot2bf(kd, b1d, ak1);                \
    ak2 = dot2bf(kd, b2d, ak2);
    DOT7(qv0.x, kv0.x, a00.x, a10.x, a20.x, b00.x, b10.x, b20.x)
    DOT7(qv0.y, kv0.y, a00.y, a10.y, a20.y, b00.y, b10.y, b20.y)
    DOT7(qv0.z, kv0.z, a00.z, a10.z, a20.z, b00.z, b10.z, b20.z)
    DOT7(qv0.w, kv0.w, a00.w, a10.w, a20.w, b00.w, b10.w, b20.w)
    DOT7(qv1.x, kv1.x, a01.x, a11.x, a21.x, b01.x, b11.x, b21.x)
    DOT7(qv1.y, kv1.y, a01.y, a11.y, a21.y, b01.y, b11.y, b21.y)
    DOT7(qv1.z, kv1.z, a01.z, a11.z, a21.z, b01.z, b11.z, b21.z)
    DOT7(qv1.w, kv1.w, a01.w, a11.w, a21.w, b01.w, b11.w, b21.w)
#undef DOT7
    acc = ((aqk + aq0) + (aq1 + aq2)) + ((ak0 + ak1) + ak2);
#else
    f32x2 acc2 = {0.0f, 0.0f};
    acc2 = dot8_pk(qv0, kv0, a00, a10, a20, b00, b10, b20, acc2);
    acc2 = dot8_pk(qv1, kv1, a01, a11, a21, b01, b11, b21, acc2);
    acc = acc2.x + acc2.y;
#endif
    // edge-local reduce over 4 dim-groups (lane bits 0..1)
    acc += __shfl_xor(acc, 1);
    acc += __shfl_xor(acc, 2);

    // in-wave softmax over 16 edges (lane bits 2..5)
    float m = acc;
    #pragma unroll
    for (int off = 4; off <= 32; off <<= 1) m = fmaxf(m, __shfl_xor(m, off));
    float ex = __expf(acc - m);
    float s = ex;
    #pragma unroll
    for (int off = 4; off <= 32; off <<= 1) s += __shfl_xor(s, off);
    const float p = ex / s;

    // V phase: p for edges e8 / e8+8 via shuffle from lane 4*e
    const float pA = __shfl(p, e8 << 2);
    const float pB = __shfl(p, (e8 + 8) << 2);
    const int vbo = c * 16;
    const uint4 tA0 = tld(s_tv, EA.x, vbo);
    const uint4 tA1 = tld(s_tv, EA.y, vbo);
    const uint4 tA2 = tld(s_tv, EA.z, vbo);
    const uint4 tB0 = tld(s_tv, EB.x, vbo);
    const uint4 tB1 = tld(s_tv, EB.y, vbo);
    const uint4 tB2 = tld(s_tv, EB.z, vbo);

    f32x2 vc[4] = {{0.f, 0.f}, {0.f, 0.f}, {0.f, 0.f}, {0.f, 0.f}};
    acc4(vc, vA, tA0, tA1, tA2, pA);
    acc4(vc, vB, tB0, tB1, tB2, pB);

    #pragma unroll
    for (int q4 = 0; q4 < 4; ++q4) {
      #pragma unroll
      for (int off = 8; off <= 32; off <<= 1) {
        vc[q4].x += __shfl_xor(vc[q4].x, off);
        vc[q4].y += __shfl_xor(vc[q4].y, off);
      }
    }
    if (e8 == 0) {
      uint4 o;
      o.x = ((unsigned)f2bf(vc[0].y) << 16) | (unsigned)f2bf(vc[0].x);
      o.y = ((unsigned)f2bf(vc[1].y) << 16) | (unsigned)f2bf(vc[1].x);
      o.z = ((unsigned)f2bf(vc[2].y) << 16) | (unsigned)f2bf(vc[2].x);
      o.w = ((unsigned)f2bf(vc[3].y) << 16) | (unsigned)f2bf(vc[3].x);
      *(uint4*)(xout + (size_t)node * CD + (b * 3 + hh) * 64 + c * 8) = o;
    }
  }
}

}  // namespace

extern "C" void kernel_launch(void* const* d_in, const int* in_sizes, int n_in,
                              void* d_out, int out_size, void* d_ws, size_t ws_size,
                              hipStream_t stream) {
  const float* qf    = (const float*)d_in[0];
  const float* xyz   = (const float*)d_in[1];
  const int*   i1c   = (const int*)d_in[3];   // index_1
  const int*   i1s   = (const int*)d_in[5];   // index_1_sphere
  const float* Wqkv  = (const float*)d_in[6];
  const float* bqkv  = (const float*)d_in[7];
  const float* Wproj = (const float*)d_in[8];
  const float* bproj = (const float*)d_in[9];
  const float* tq    = (const float*)d_in[10];
  const float* tk    = (const float*)d_in[11];
  const float* tv    = (const float*)d_in[12];
  const float* tqs   = (const float*)d_in[13];
  const float* tks   = (const float*)d_in[14];
  const float* tvs   = (const float*)d_in[15];

  char* w = (char*)d_ws;
  unsigned short* qf_b   = (unsigned short*)w; w += (size_t)NP * CD * 2;    // 15.36 MB
  unsigned short* wqkvT  = (unsigned short*)w; w += (size_t)QKVD * CD * 2;  // 0.88 MB
  unsigned short* wprojT = (unsigned short*)w; w += (size_t)CD * CD * 2;    // 0.29 MB
  unsigned short* qkv_b  = (unsigned short*)w; w += (size_t)NP * QKVD * 2;  // 46.08 MB
  unsigned short* x_b    = (unsigned short*)w; w += (size_t)NP * CD * 2;    // 15.36 MB
  float*          sph    = (float*)w;          w += (size_t)NP * 3 * 4;     // 0.24 MB
  unsigned short* tq_b   = (unsigned short*)w; w += (size_t)TC * 2;
  unsigned short* tk_b   = (unsigned short*)w; w += (size_t)TC * 2;
  unsigned short* tv_b   = (unsigned short*)w; w += (size_t)TC * 2;
  unsigned short* tqs_b  = (unsigned short*)w; w += (size_t)TS * 2;
  unsigned short* tks_b  = (unsigned short*)w; w += (size_t)TS * 2;
  unsigned short* tvs_b  = (unsigned short*)w; w += (size_t)TS * 2;
  int4*           ebuf   = (int4*)w;           // 10.24 MB

  prep_all_k<<<PB3, 256, 0, stream>>>(qf, qf_b, Wqkv, wqkvT, Wproj, wprojT,
                                      tq, tk, tv, tqs, tks, tvs,
                                      tq_b, tk_b, tv_b, tqs_b, tks_b, tvs_b,
                                      xyz, sph);

  bin_k<<<(2 * NP * 16 + 255) / 256, 256, 0, stream>>>(xyz, sph, i1c, i1s, ebuf);

  gemm_async_k<0><<<((NP + 127) / 128) * (QKVD / 128), 256, 0, stream>>>(
      (const short*)qf_b, (const short*)wqkvT, bqkv, qkv_b, NP, QKVD, CD);

  attn_lds_k<<<dim3(3, ANY), 1024, 0, stream>>>(qkv_b, ebuf,
                                                tq_b, tk_b, tv_b,
                                                tqs_b, tks_b, tvs_b, x_b, 0);
  attn_lds_k<<<dim3(3, ANY), 1024, 0, stream>>>(qkv_b, ebuf,
                                                tq_b, tk_b, tv_b,
                                                tqs_b, tks_b, tvs_b, x_b, 3);

  gemm_async_k<1><<<((NP + 127) / 128) * (CD / 128), 256, 0, stream>>>(
      (const short*)x_b, (const short*)wprojT, bproj, d_out, NP, CD, CD);
}

// Round 15
// 279.899 us; speedup vs baseline: 1.2061x; 1.0163x over previous
//
#include <hip/hip_runtime.h>
#include <hip/hip_bf16.h>

namespace {

constexpr int NP   = 20000;   // points
constexpr int CD   = 384;     // channels
constexpr int QKVD = 1152;    // 3*C
constexpr int TC   = 47 * 3 * 3 * 64;   // 27072 cart-table elems
constexpr int TS   = 48 * 3 * 3 * 64;   // 27648 sphere-table elems

// merged-prep block ranges (R15: bin_k folded in; sph computed inline)
constexpr int PB0 = NP * CD / 4 / 256;              // 7500  cvt qf
constexpr int PB1 = PB0 + (QKVD / 32) * (CD / 32);  // +432 transpose Wqkv
constexpr int PB2 = PB1 + (CD / 32) * (CD / 32);    // +144 transpose Wproj
constexpr int PB3 = PB2 + 27 * 6;                   // +162 table cvt
constexpr int PB4 = PB3 + 2 * NP * 16 / 256;        // +2500 edge binning

// attn geometry (R11 config — best measured: 108.5us fused)
constexpr int ANB = 240;                        // nodes per block
constexpr int ANY = (NP + ANB - 1) / ANB;       // 84 y-blocks

typedef __attribute__((ext_vector_type(8))) short short8;
typedef __attribute__((ext_vector_type(4))) float f32x4;
typedef __attribute__((ext_vector_type(2))) float f32x2;

// Correctly-rounded fp32 transcendentals via double (match reference libm).
__device__ inline float f32_atan2(float y, float x) {
  return (float)atan2((double)y, (double)x);
}
__device__ inline float f32_log(float x) {
  return (float)log((double)x);
}

__device__ inline float bfl(unsigned u) {   // low bf16 of dword -> f32
  union { unsigned u; float f; } c; c.u = u << 16; return c.f;
}
__device__ inline float bfh(unsigned u) {   // high bf16 of dword -> f32
  union { unsigned u; float f; } c; c.u = u & 0xffff0000u; return c.f;
}
__device__ inline f32x2 up2(unsigned u) {   // dword of 2 bf16 -> packed f32x2
  f32x2 r;
  r.x = bfl(u);
  r.y = bfh(u);
  return r;
}
__device__ inline unsigned short f2bf(float x) {
  __hip_bfloat16 hb = __float2bfloat16(x);
  unsigned short u; __builtin_memcpy(&u, &hb, 2);
  return u;
}

// HW bf16 dot2: d = a.x*b.x + a.y*b.y + c in one VALU op.
#if __has_builtin(__builtin_amdgcn_fdot2_f32_bf16)
#define HAVE_BF16_DOT 1
typedef __attribute__((ext_vector_type(2))) __bf16 bf16x2_t;
__device__ inline float dot2bf(unsigned a, unsigned b, float c) {
  bf16x2_t av, bv;
  __builtin_memcpy(&av, &a, 4);
  __builtin_memcpy(&bv, &b, 4);
  return __builtin_amdgcn_fdot2_f32_bf16(av, bv, c, false);
}
#endif

// async 16B global -> LDS (global_load_lds_dwordx4). LDS dest must be the
// wave-uniform base; HW adds lane*16.
__device__ inline void async16(const void* g, void* l) {
  __builtin_amdgcn_global_load_lds(
      (const __attribute__((address_space(1))) unsigned int*)g,
      (__attribute__((address_space(3))) unsigned int*)l,
      16, 0, 0);
}

// XOR-swizzled 16B LDS table access: row*128B rows; XOR row&7 into byte
// bits 4..6 so random-row reads spread across the 8 16B slots (G4 fix).
__device__ inline uint4 tld(const char* t, int row, int bo) {
  return *(const uint4*)(t + row * 128 + (bo ^ ((row & 7) << 4)));
}
__device__ inline void tst(char* t, int row, int bo, uint4 v) {
  *(uint4*)(t + row * 128 + (bo ^ ((row & 7) << 4))) = v;
}

// ---- merged prep: cvt qf, transposes, table cvt, edge binning --------------
// R15: bin_k folded in as blocks [PB3, PB4). Binning no longer reads a
// precomputed sph[] — cart2sphere is recomputed inline per endpoint
// (deterministic fp32 fn of xyz, contract-off -> bit-identical to the
// buffered version). Removes one dispatch + the sph buffer.
__global__ __launch_bounds__(256) void prep_all_k(const float* __restrict__ qf,
                                                  unsigned short* __restrict__ qf_b,
                                                  const float* __restrict__ Wqkv,
                                                  unsigned short* __restrict__ wqkvT,
                                                  const float* __restrict__ Wproj,
                                                  unsigned short* __restrict__ wprojT,
                                                  const float* __restrict__ tq,
                                                  const float* __restrict__ tk,
                                                  const float* __restrict__ tv,
                                                  const float* __restrict__ tqs,
                                                  const float* __restrict__ tks,
                                                  const float* __restrict__ tvs,
                                                  unsigned short* __restrict__ tq_b,
                                                  unsigned short* __restrict__ tk_b,
                                                  unsigned short* __restrict__ tv_b,
                                                  unsigned short* __restrict__ tqs_b,
                                                  unsigned short* __restrict__ tks_b,
                                                  unsigned short* __restrict__ tvs_b,
                                                  const float* __restrict__ xyz,
                                                  const int* __restrict__ nb_c,
                                                  const int* __restrict__ nb_s,
                                                  int4* __restrict__ ebuf) {
  const int bid = blockIdx.x;
  const int tid = threadIdx.x;
  __shared__ float t[32][33];

  if (bid < PB0) {
    int i = (bid * 256 + tid) * 4;
    float4 v = *(const float4*)(qf + i);
    ushort4 o;
    o.x = f2bf(v.x); o.y = f2bf(v.y); o.z = f2bf(v.z); o.w = f2bf(v.w);
    *(ushort4*)(qf_b + i) = o;
  } else if (bid < PB2) {
    const float* in;
    unsigned short* out;
    int R, Cc, bx, by;
    if (bid < PB1) {
      in = Wqkv; out = wqkvT; R = CD; Cc = QKVD;
      int tt = bid - PB0; bx = tt % (QKVD / 32); by = tt / (QKVD / 32);
    } else {
      in = Wproj; out = wprojT; R = CD; Cc = CD;
      int tt = bid - PB1; bx = tt % (CD / 32); by = tt / (CD / 32);
    }
    const int c0 = bx * 32, r0 = by * 32;
    const int tx = tid & 31, ty = tid >> 5;
    #pragma unroll
    for (int i = 0; i < 32; i += 8)
      t[ty + i][tx] = in[(size_t)(r0 + ty + i) * Cc + (c0 + tx)];
    __syncthreads();
    #pragma unroll
    for (int i = 0; i < 32; i += 8)
      out[(size_t)(c0 + ty + i) * R + (r0 + tx)] = f2bf(t[tx][ty + i]);
  } else if (bid < PB3) {
    const int tt = bid - PB2;
    const int bx = tt % 27, y = tt / 27;   // y in 0..5
    const int th = bx * 256 + tid;
    const float* in = (y == 0) ? tq : (y == 1) ? tk : (y == 2) ? tv
                    : (y == 3) ? tqs : (y == 4) ? tks : tvs;
    unsigned short* out = (y == 0) ? tq_b : (y == 1) ? tk_b : (y == 2) ? tv_b
                        : (y == 3) ? tqs_b : (y == 4) ? tks_b : tvs_b;
    const int n = (y < 3) ? TC : TS;   // both divisible by 4
    int i = th * 4;
    if (i < n) {
      float4 v = *(const float4*)(in + i);
      ushort4 o;
      o.x = f2bf(v.x); o.y = f2bf(v.y); o.z = f2bf(v.z); o.w = f2bf(v.w);
      *(ushort4*)(out + i) = o;
    }
  } else {
    // ---- edge binning: one thread per (branch, node, edge) ----------------
    // ebuf[(b*NP + n)*16 + e] = {row0, row1, row2, i1}, row = idx*3+dim.
#pragma clang fp contract(off)
    const int t2  = (bid - PB3) * 256 + tid;     // < 2*NP*16 exactly
    const int b   = t2 / (NP * 16);
    const int rem = t2 - b * NP * 16;
    const int n   = rem >> 4;
    const int e   = rem & 15;
    int4 o;
    if (b == 0) {
      const int i1 = nb_c[n * 16 + e];
      const float rel[3] = {xyz[n * 3 + 0] - xyz[i1 * 3 + 0],
                            xyz[n * 3 + 1] - xyz[i1 * 3 + 1],
                            xyz[n * 3 + 2] - xyz[i1 * 3 + 2]};
      int r[3];
      #pragma unroll
      for (int dim = 0; dim < 3; ++dim) {
        int idx = (int)floorf(rel[dim] * 4.0f) + 23;
        idx = min(max(idx, 0), 46);
        r[dim] = idx * 3 + dim;
      }
      o.x = r[0]; o.y = r[1]; o.z = r[2]; o.w = i1;
    } else {
      const int i1 = nb_s[n * 16 + e];
      const float PIF = 3.14159265358979323846f;
      const float R2D = 57.29577951308232f;
      // inline cart2sphere for both endpoints (bit-exact vs buffered)
      float xn = xyz[n * 3 + 0], yn = xyz[n * 3 + 1], zn = xyz[n * 3 + 2];
      float sxyn = xn * xn + yn * yn;
      const float tn0 = (f32_atan2(yn, xn) + PIF) * R2D;
      const float tn1 = f32_atan2(sqrtf(sxyn), zn) * R2D;
      const float tn2 = sqrtf(sxyn + zn * zn);
      float xm = xyz[i1 * 3 + 0], ym = xyz[i1 * 3 + 1], zm = xyz[i1 * 3 + 2];
      float sxym = xm * xm + ym * ym;
      const float tm0 = (f32_atan2(ym, xm) + PIF) * R2D;
      const float tm1 = f32_atan2(sqrtf(sxym), zm) * R2D;
      const float tm2 = sqrtf(sxym + zm * zm);
      const float d0 = tn0 - tm0;
      const float d1 = tn1 - tm1;
      const float dr = tn2 - tm2;
      int i0a = (int)floorf(d0 / 5.0f) + 24;
      int i1a = (int)floorf(d1 / 5.0f) + 24;
      const float ra = fabsf(dr);
      const float flag = (dr >= 0.0f) ? 1.0f : 0.0f;
      const float tt = (ra + 0.025f) / 0.0125f;
      const float wv = f32_log(tt) / 0.69314718055994531f;
      float fidx = 2.0f * floorf(wv) - 2.0f;
      fidx += ((3.0f * exp2f(floorf(fidx * 0.5f)) - 2.0f) * 0.0125f <= ra) ? 1.0f : 0.0f;
      fidx = fidx * (2.0f * flag - 1.0f) + (flag - 1.0f);
      int i2a = (int)fidx + 24;
      o.x = min(max(i0a, 0), 47) * 3 + 0;
      o.y = min(max(i1a, 0), 47) * 3 + 1;
      o.z = min(max(i2a, 0), 47) * 3 + 2;
      o.w = i1;
    }
    ebuf[t2] = o;
  }
}

// ------- bf16 MFMA GEMM: 3-buffer depth-2 prefetch + XCD chunk remap --------
// (R9 version — best measured. R13's direct-from-global variant was 57us
// slower.) Ledger (per wave, 4 loads/stage): top of iter t outstanding =
// {t,t+1} = 8; vmcnt(4) drains exactly tile t; buffers t%3 disjoint for
// {t,t+1,t+2}; buf (t+2)%3 last read before barrier2(t-1).
// MODE 0: bf16 out, scale cols < 384 by 0.125. MODE 1: fp32 out.
template <int MODE>
__global__ __launch_bounds__(256) void gemm_async_k(const short* __restrict__ A,
                                                    const short* __restrict__ BT,
                                                    const float* __restrict__ bias,
                                                    void* __restrict__ Cout,
                                                    int M, int Nn, int K) {
  __shared__ short As[3][128][32];
  __shared__ short Bs[3][128][32];
  const int tid  = threadIdx.x;

  // bijective XCD chunk remap (m204): xcd = orig%8 gets contiguous wg range.
  const int NT  = Nn >> 7;
  const int nwg = gridDim.x;
  const int q = nwg >> 3, r = nwg & 7;
  const int xcd = blockIdx.x & 7, j = blockIdx.x >> 3;
  const int wg = (xcd < r ? xcd * (q + 1) : r * (q + 1) + (xcd - r) * q) + j;
  const int m0 = (wg / NT) * 128, n0 = (wg % NT) * 128;

  const int wave = tid >> 6, lane = tid & 63;
  const int wm   = (wave & 1) * 64, wn = (wave >> 1) * 64;
  const int quad = lane >> 4, l16 = lane & 15;
  const int srow = lane >> 2;
  const int scol = (lane & 3) * 8;   // shorts

  f32x4 acc[4][4] = {};

  auto stage = [&](int buf, int k0) {
    #pragma unroll
    for (int c = 0; c < 2; ++c) {
      const int base = (wave + c * 4) * 16;      // wave-uniform: 0..112
      async16(A + (size_t)(m0 + base + srow) * K + k0 + scol, &As[buf][base][0]);
      async16(BT + (size_t)(n0 + base + srow) * K + k0 + scol, &Bs[buf][base][0]);
    }
  };

  const int nt = K >> 5;          // K/32 tiles (>=2 for both call sites)
  stage(0, 0);
  stage(1, 32);
  for (int t = 0; t < nt; ++t) {
    const int cur = t % 3;
    if (t + 1 < nt) {
      asm volatile("s_waitcnt vmcnt(4)" ::: "memory");   // tile t landed
    } else {
      asm volatile("s_waitcnt vmcnt(0)" ::: "memory");
    }
    __builtin_amdgcn_s_barrier();   // all waves: tile t staged
    short8 af[4], bg[4];
    #pragma unroll
    for (int i = 0; i < 4; ++i) af[i] = *(const short8*)&As[cur][wm + i * 16 + l16][quad * 8];
    #pragma unroll
    for (int j2 = 0; j2 < 4; ++j2) bg[j2] = *(const short8*)&Bs[cur][wn + j2 * 16 + l16][quad * 8];
    #pragma unroll
    for (int i = 0; i < 4; ++i)
      #pragma unroll
      for (int j2 = 0; j2 < 4; ++j2)
        acc[i][j2] = __builtin_amdgcn_mfma_f32_16x16x32_bf16(af[i], bg[j2], acc[i][j2], 0, 0, 0);
    __builtin_amdgcn_s_barrier();   // all reads of tile t done before re-stage
    if (t + 2 < nt) stage((t + 2) % 3, (t + 2) * 32);
  }

  #pragma unroll
  for (int i = 0; i < 4; ++i) {
    #pragma unroll
    for (int r2 = 0; r2 < 4; ++r2) {
      const int gm = m0 + wm + i * 16 + quad * 4 + r2;
      if (gm >= M) continue;
      #pragma unroll
      for (int j2 = 0; j2 < 4; ++j2) {
        const int gn = n0 + wn + j2 * 16 + l16;
        if (gn >= Nn) continue;
        float v = acc[i][j2][r2] + bias[gn];
        if (MODE == 0) {
          if (gn < 384) v *= 0.125f;   // SCALE = 64^-0.5
          ((unsigned short*)Cout)[(size_t)gm * Nn + gn] = f2bf(v);
        } else {
          ((float*)Cout)[(size_t)gm * Nn + gn] = v;
        }
      }
    }
  }
}

// 8-dim partial, packed f32 math (fallback when no HW bf16 dot).
__device__ inline f32x2 dot8_pk(uint4 q, uint4 k, uint4 a0, uint4 a1, uint4 a2,
                                uint4 t0, uint4 t1, uint4 t2, f32x2 acc) {
  const unsigned* qp = &q.x;  const unsigned* kp = &k.x;
  const unsigned* a0p = &a0.x; const unsigned* a1p = &a1.x; const unsigned* a2p = &a2.x;
  const unsigned* t0p = &t0.x; const unsigned* t1p = &t1.x; const unsigned* t2p = &t2.x;
  #pragma unroll
  for (int w2 = 0; w2 < 4; ++w2) {
    f32x2 qf = up2(qp[w2]), kf = up2(kp[w2]);
    f32x2 tqs = up2(a0p[w2]) + up2(a1p[w2]) + up2(a2p[w2]);
    f32x2 tks = up2(t0p[w2]) + up2(t1p[w2]) + up2(t2p[w2]);
    acc += qf * (kf + tqs) + kf * tks;
  }
  return acc;
}

// V-phase accumulate: vc[0..3] += pr * (vv + t0 + t1 + t2), per-dword packed.
__device__ inline void acc4(f32x2* vc, uint4 vv, uint4 t0, uint4 t1, uint4 t2,
                            float pr) {
  f32x2 prv = {pr, pr};
  vc[0] += prv * (up2(vv.x) + up2(t0.x) + up2(t1.x) + up2(t2.x));
  vc[1] += prv * (up2(vv.y) + up2(t0.y) + up2(t1.y) + up2(t2.y));
  vc[2] += prv * (up2(vv.z) + up2(t0.z) + up2(t1.z) + up2(t2.z));
  vc[3] += prv * (up2(vv.w) + up2(t0.w) + up2(t1.w) + up2(t2.w));
}

// -------- fused sparse attention, LDS-staged tables, 16-wave blocks ---------
// R11 config verbatim (best measured: 108.5us, single dispatch).
__global__ __launch_bounds__(1024, 4) void attn_lds_k(const unsigned short* __restrict__ qkv,
                                                      const int4* __restrict__ ebuf,
                                                      const unsigned short* __restrict__ tq_c,
                                                      const unsigned short* __restrict__ tk_c,
                                                      const unsigned short* __restrict__ tv_c,
                                                      const unsigned short* __restrict__ tq_s,
                                                      const unsigned short* __restrict__ tk_s,
                                                      const unsigned short* __restrict__ tv_s,
                                                      unsigned short* __restrict__ xout) {
  __shared__ char s_tq[144 * 128];
  __shared__ char s_tk[144 * 128];
  __shared__ char s_tv[144 * 128];

  const int bh  = blockIdx.x;      // 0..5
  const int b   = bh / 3;          // branch
  const int hh  = bh % 3;          // head within branch
  const int wid = threadIdx.x >> 6, lane = threadIdx.x & 63;

  const unsigned short* gtq = b ? tq_s : tq_c;
  const unsigned short* gtk = b ? tk_s : tk_c;
  const unsigned short* gtv = b ? tv_s : tv_c;
  const int nrows = b ? 144 : 141;

  // ---- stage table head-slices into LDS (row = r*3+d, 128B rows) ----------
  for (int i = threadIdx.x; i < nrows * 8; i += 1024) {
    const int row = i >> 3, c8 = i & 7;
    const int go = row * 192 + hh * 64 + c8 * 8;   // global elem offset
    tst(s_tq, row, c8 * 16, *(const uint4*)(gtq + go));
    tst(s_tk, row, c8 * 16, *(const uint4*)(gtk + go));
    tst(s_tv, row, c8 * 16, *(const uint4*)(gtv + go));
  }
  __syncthreads();

  const int eg = lane >> 2, g = lane & 3;       // logits mapping
  const int e8 = lane >> 3, c = lane & 7;       // V mapping
  const int node_end = min(blockIdx.y * ANB + ANB, NP);

  for (int node = blockIdx.y * ANB + wid; node < node_end; node += 16) {
    const int4* eb = ebuf + ((size_t)b * NP + node) * 16;

    // per-lane index loads (coalesced 4/8-dup within 256B)
    const int4 E  = eb[eg];                     // logits edge
    const int4 EA = eb[e8];                     // V edges
    const int4 EB = eb[e8 + 8];

    // q + k + v global loads issued up front (v flies under logits+softmax)
    const unsigned short* qp = qkv + (size_t)node * QKVD + b * 192 + hh * 64 + g * 16;
    const uint4 qv0 = *(const uint4*)(qp);
    const uint4 qv1 = *(const uint4*)(qp + 8);
    const unsigned short* kp = qkv + (size_t)E.w * QKVD + 384 + b * 192 + hh * 64 + g * 16;
    const uint4 kv0 = *(const uint4*)(kp);
    const uint4 kv1 = *(const uint4*)(kp + 8);
    const int hc = hh * 64 + c * 8;
    const uint4 vA = *(const uint4*)(qkv + (size_t)EA.w * QKVD + 768 + b * 192 + hc);
    const uint4 vB = *(const uint4*)(qkv + (size_t)EB.w * QKVD + 768 + b * 192 + hc);

    // table operands from LDS (swizzled)
    const int bo = g * 32;
    const uint4 a00 = tld(s_tq, E.x, bo), a01 = tld(s_tq, E.x, bo + 16);
    const uint4 a10 = tld(s_tq, E.y, bo), a11 = tld(s_tq, E.y, bo + 16);
    const uint4 a20 = tld(s_tq, E.z, bo), a21 = tld(s_tq, E.z, bo + 16);
    const uint4 b00 = tld(s_tk, E.x, bo), b01 = tld(s_tk, E.x, bo + 16);
    const uint4 b10 = tld(s_tk, E.y, bo), b11 = tld(s_tk, E.y, bo + 16);
    const uint4 b20 = tld(s_tk, E.z, bo), b21 = tld(s_tk, E.z, bo + 16);

    float acc;
#ifdef HAVE_BF16_DOT
    float aqk = 0.0f, aq0 = 0.0f, aq1 = 0.0f, aq2 = 0.0f;
    float ak0 = 0.0f, ak1 = 0.0f, ak2 = 0.0f;
#define DOT7(qd, kd, a0d, a1d, a2d, b0d, b1d, b2d)                         \
    aqk = dot2bf(qd, kd, aqk);  aq0 = dot2bf(qd, a0d, aq0);                \
    aq1 = dot2bf(qd, a1d, aq1); aq2 = dot2bf(qd, a2d, aq2);                \
    ak0 = dot2bf(kd, b0d, ak0); ak1 = dot2bf(kd, b1d, ak1);                \
    ak2 = dot2bf(kd, b2d, ak2);
    DOT7(qv0.x, kv0.x, a00.x, a10.x, a20.x, b00.x, b10.x, b20.x)
    DOT7(qv0.y, kv0.y, a00.y, a10.y, a20.y, b00.y, b10.y, b20.y)
    DOT7(qv0.z, kv0.z, a00.z, a10.z, a20.z, b00.z, b10.z, b20.z)
    DOT7(qv0.w, kv0.w, a00.w, a10.w, a20.w, b00.w, b10.w, b20.w)
    DOT7(qv1.x, kv1.x, a01.x, a11.x, a21.x, b01.x, b11.x, b21.x)
    DOT7(qv1.y, kv1.y, a01.y, a11.y, a21.y, b01.y, b11.y, b21.y)
    DOT7(qv1.z, kv1.z, a01.z, a11.z, a21.z, b01.z, b11.z, b21.z)
    DOT7(qv1.w, kv1.w, a01.w, a11.w, a21.w, b01.w, b11.w, b21.w)
#undef DOT7
    acc = ((aqk + aq0) + (aq1 + aq2)) + ((ak0 + ak1) + ak2);
#else
    f32x2 acc2 = {0.0f, 0.0f};
    acc2 = dot8_pk(qv0, kv0, a00, a10, a20, b00, b10, b20, acc2);
    acc2 = dot8_pk(qv1, kv1, a01, a11, a21, b01, b11, b21, acc2);
    acc = acc2.x + acc2.y;
#endif
    // edge-local reduce over 4 dim-groups (lane bits 0..1)
    acc += __shfl_xor(acc, 1);
    acc += __shfl_xor(acc, 2);

    // in-wave softmax over 16 edges (lane bits 2..5)
    float m = acc;
    #pragma unroll
    for (int off = 4; off <= 32; off <<= 1) m = fmaxf(m, __shfl_xor(m, off));
    float ex = __expf(acc - m);
    float s = ex;
    #pragma unroll
    for (int off = 4; off <= 32; off <<= 1) s += __shfl_xor(s, off);
    const float p = ex / s;

    // V phase: p for edges e8 / e8+8 via shuffle from lane 4*e
    const float pA = __shfl(p, e8 << 2);
    const float pB = __shfl(p, (e8 + 8) << 2);
    const int vbo = c * 16;
    const uint4 tA0 = tld(s_tv, EA.x, vbo);
    const uint4 tA1 = tld(s_tv, EA.y, vbo);
    const uint4 tA2 = tld(s_tv, EA.z, vbo);
    const uint4 tB0 = tld(s_tv, EB.x, vbo);
    const uint4 tB1 = tld(s_tv, EB.y, vbo);
    const uint4 tB2 = tld(s_tv, EB.z, vbo);

    f32x2 vc[4] = {{0.f, 0.f}, {0.f, 0.f}, {0.f, 0.f}, {0.f, 0.f}};
    acc4(vc, vA, tA0, tA1, tA2, pA);
    acc4(vc, vB, tB0, tB1, tB2, pB);

    #pragma unroll
    for (int q4 = 0; q4 < 4; ++q4) {
      #pragma unroll
      for (int off = 8; off <= 32; off <<= 1) {
        vc[q4].x += __shfl_xor(vc[q4].x, off);
        vc[q4].y += __shfl_xor(vc[q4].y, off);
      }
    }
    if (e8 == 0) {
      uint4 o;
      o.x = ((unsigned)f2bf(vc[0].y) << 16) | (unsigned)f2bf(vc[0].x);
      o.y = ((unsigned)f2bf(vc[1].y) << 16) | (unsigned)f2bf(vc[1].x);
      o.z = ((unsigned)f2bf(vc[2].y) << 16) | (unsigned)f2bf(vc[2].x);
      o.w = ((unsigned)f2bf(vc[3].y) << 16) | (unsigned)f2bf(vc[3].x);
      *(uint4*)(xout + (size_t)node * CD + (b * 3 + hh) * 64 + c * 8) = o;
    }
  }
}

}  // namespace

extern "C" void kernel_launch(void* const* d_in, const int* in_sizes, int n_in,
                              void* d_out, int out_size, void* d_ws, size_t ws_size,
                              hipStream_t stream) {
  const float* qf    = (const float*)d_in[0];
  const float* xyz   = (const float*)d_in[1];
  const int*   i1c   = (const int*)d_in[3];   // index_1
  const int*   i1s   = (const int*)d_in[5];   // index_1_sphere
  const float* Wqkv  = (const float*)d_in[6];
  const float* bqkv  = (const float*)d_in[7];
  const float* Wproj = (const float*)d_in[8];
  const float* bproj = (const float*)d_in[9];
  const float* tq    = (const float*)d_in[10];
  const float* tk    = (const float*)d_in[11];
  const float* tv    = (const float*)d_in[12];
  const float* tqs   = (const float*)d_in[13];
  const float* tks   = (const float*)d_in[14];
  const float* tvs   = (const float*)d_in[15];

  char* w = (char*)d_ws;
  unsigned short* qf_b   = (unsigned short*)w; w += (size_t)NP * CD * 2;    // 15.36 MB
  unsigned short* wqkvT  = (unsigned short*)w; w += (size_t)QKVD * CD * 2;  // 0.88 MB
  unsigned short* wprojT = (unsigned short*)w; w += (size_t)CD * CD * 2;    // 0.29 MB
  unsigned short* qkv_b  = (unsigned short*)w; w += (size_t)NP * QKVD * 2;  // 46.08 MB
  unsigned short* x_b    = (unsigned short*)w; w += (size_t)NP * CD * 2;    // 15.36 MB
  unsigned short* tq_b   = (unsigned short*)w; w += (size_t)TC * 2;
  unsigned short* tk_b   = (unsigned short*)w; w += (size_t)TC * 2;
  unsigned short* tv_b   = (unsigned short*)w; w += (size_t)TC * 2;
  unsigned short* tqs_b  = (unsigned short*)w; w += (size_t)TS * 2;
  unsigned short* tks_b  = (unsigned short*)w; w += (size_t)TS * 2;
  unsigned short* tvs_b  = (unsigned short*)w; w += (size_t)TS * 2;
  int4*           ebuf   = (int4*)w;           // 10.24 MB

  prep_all_k<<<PB4, 256, 0, stream>>>(qf, qf_b, Wqkv, wqkvT, Wproj, wprojT,
                                      tq, tk, tv, tqs, tks, tvs,
                                      tq_b, tk_b, tv_b, tqs_b, tks_b, tvs_b,
                                      xyz, i1c, i1s, ebuf);

  gemm_async_k<0><<<((NP + 127) / 128) * (QKVD / 128), 256, 0, stream>>>(
      (const short*)qf_b, (const short*)wqkvT, bqkv, qkv_b, NP, QKVD, CD);

  attn_lds_k<<<dim3(6, ANY), 1024, 0, stream>>>(qkv_b, ebuf,
                                                tq_b, tk_b, tv_b,
                                                tqs_b, tks_b, tvs_b, x_b);

  gemm_async_k<1><<<((NP + 127) / 128) * (CD / 128), 256, 0, stream>>>(
      (const short*)x_b, (const short*)wprojT, bproj, d_out, NP, CD, CD);
}

// Round 16
// 264.611 us; speedup vs baseline: 1.2758x; 1.0578x over previous
//
#include <hip/hip_runtime.h>
#include <hip/hip_bf16.h>

namespace {

constexpr int NP   = 20000;   // points
constexpr int CD   = 384;     // channels
constexpr int QKVD = 1152;    // 3*C
constexpr int TC   = 47 * 3 * 3 * 64;   // 27072 cart-table elems
constexpr int TS   = 48 * 3 * 3 * 64;   // 27648 sphere-table elems

// merged-prep block ranges (R15: bin_k folded in; sph computed inline)
constexpr int PB0 = NP * CD / 4 / 256;              // 7500  cvt qf
constexpr int PB1 = PB0 + (QKVD / 32) * (CD / 32);  // +432 transpose Wqkv
constexpr int PB2 = PB1 + (CD / 32) * (CD / 32);    // +144 transpose Wproj
constexpr int PB3 = PB2 + 27 * 6;                   // +162 table cvt
constexpr int PB4 = PB3 + 2 * NP * 16 / 256;        // +2500 edge binning

// attn geometry (R11 config — best measured: 108.5us fused)
constexpr int ANB = 240;                        // nodes per block
constexpr int ANY = (NP + ANB - 1) / ANB;       // 84 y-blocks

typedef __attribute__((ext_vector_type(8))) short short8;
typedef __attribute__((ext_vector_type(4))) float f32x4;
typedef __attribute__((ext_vector_type(2))) float f32x2;

// Correctly-rounded fp32 transcendentals via double (match reference libm).
__device__ inline float f32_atan2(float y, float x) {
  return (float)atan2((double)y, (double)x);
}
__device__ inline float f32_log(float x) {
  return (float)log((double)x);
}

__device__ inline float bfl(unsigned u) {   // low bf16 of dword -> f32
  union { unsigned u; float f; } c; c.u = u << 16; return c.f;
}
__device__ inline float bfh(unsigned u) {   // high bf16 of dword -> f32
  union { unsigned u; float f; } c; c.u = u & 0xffff0000u; return c.f;
}
__device__ inline f32x2 up2(unsigned u) {   // dword of 2 bf16 -> packed f32x2
  f32x2 r;
  r.x = bfl(u);
  r.y = bfh(u);
  return r;
}
__device__ inline unsigned short f2bf(float x) {
  __hip_bfloat16 hb = __float2bfloat16(x);
  unsigned short u; __builtin_memcpy(&u, &hb, 2);
  return u;
}

// HW bf16 dot2: d = a.x*b.x + a.y*b.y + c in one VALU op.
#if __has_builtin(__builtin_amdgcn_fdot2_f32_bf16)
#define HAVE_BF16_DOT 1
typedef __attribute__((ext_vector_type(2))) __bf16 bf16x2_t;
__device__ inline float dot2bf(unsigned a, unsigned b, float c) {
  bf16x2_t av, bv;
  __builtin_memcpy(&av, &a, 4);
  __builtin_memcpy(&bv, &b, 4);
  return __builtin_amdgcn_fdot2_f32_bf16(av, bv, c, false);
}
#endif

// async 16B global -> LDS (global_load_lds_dwordx4). LDS dest must be the
// wave-uniform base; HW adds lane*16.
__device__ inline void async16(const void* g, void* l) {
  __builtin_amdgcn_global_load_lds(
      (const __attribute__((address_space(1))) unsigned int*)g,
      (__attribute__((address_space(3))) unsigned int*)l,
      16, 0, 0);
}

// XOR-swizzled 16B LDS table access: row*128B rows; XOR row&7 into byte
// bits 4..6 so random-row reads spread across the 8 16B slots (G4 fix).
__device__ inline uint4 tld(const char* t, int row, int bo) {
  return *(const uint4*)(t + row * 128 + (bo ^ ((row & 7) << 4)));
}
__device__ inline void tst(char* t, int row, int bo, uint4 v) {
  *(uint4*)(t + row * 128 + (bo ^ ((row & 7) << 4))) = v;
}

// ---- merged prep: cvt qf, transposes, table cvt, edge binning --------------
// Binning recomputes cart2sphere inline per endpoint (bit-exact vs the old
// buffered version; deterministic fp32 fn of xyz, contract-off).
__global__ __launch_bounds__(256) void prep_all_k(const float* __restrict__ qf,
                                                  unsigned short* __restrict__ qf_b,
                                                  const float* __restrict__ Wqkv,
                                                  unsigned short* __restrict__ wqkvT,
                                                  const float* __restrict__ Wproj,
                                                  unsigned short* __restrict__ wprojT,
                                                  const float* __restrict__ tq,
                                                  const float* __restrict__ tk,
                                                  const float* __restrict__ tv,
                                                  const float* __restrict__ tqs,
                                                  const float* __restrict__ tks,
                                                  const float* __restrict__ tvs,
                                                  unsigned short* __restrict__ tq_b,
                                                  unsigned short* __restrict__ tk_b,
                                                  unsigned short* __restrict__ tv_b,
                                                  unsigned short* __restrict__ tqs_b,
                                                  unsigned short* __restrict__ tks_b,
                                                  unsigned short* __restrict__ tvs_b,
                                                  const float* __restrict__ xyz,
                                                  const int* __restrict__ nb_c,
                                                  const int* __restrict__ nb_s,
                                                  int4* __restrict__ ebuf) {
  const int bid = blockIdx.x;
  const int tid = threadIdx.x;
  __shared__ float t[32][33];

  if (bid < PB0) {
    int i = (bid * 256 + tid) * 4;
    float4 v = *(const float4*)(qf + i);
    ushort4 o;
    o.x = f2bf(v.x); o.y = f2bf(v.y); o.z = f2bf(v.z); o.w = f2bf(v.w);
    *(ushort4*)(qf_b + i) = o;
  } else if (bid < PB2) {
    const float* in;
    unsigned short* out;
    int R, Cc, bx, by;
    if (bid < PB1) {
      in = Wqkv; out = wqkvT; R = CD; Cc = QKVD;
      int tt = bid - PB0; bx = tt % (QKVD / 32); by = tt / (QKVD / 32);
    } else {
      in = Wproj; out = wprojT; R = CD; Cc = CD;
      int tt = bid - PB1; bx = tt % (CD / 32); by = tt / (CD / 32);
    }
    const int c0 = bx * 32, r0 = by * 32;
    const int tx = tid & 31, ty = tid >> 5;
    #pragma unroll
    for (int i = 0; i < 32; i += 8)
      t[ty + i][tx] = in[(size_t)(r0 + ty + i) * Cc + (c0 + tx)];
    __syncthreads();
    #pragma unroll
    for (int i = 0; i < 32; i += 8)
      out[(size_t)(c0 + ty + i) * R + (r0 + tx)] = f2bf(t[tx][ty + i]);
  } else if (bid < PB3) {
    const int tt = bid - PB2;
    const int bx = tt % 27, y = tt / 27;   // y in 0..5
    const int th = bx * 256 + tid;
    const float* in = (y == 0) ? tq : (y == 1) ? tk : (y == 2) ? tv
                    : (y == 3) ? tqs : (y == 4) ? tks : tvs;
    unsigned short* out = (y == 0) ? tq_b : (y == 1) ? tk_b : (y == 2) ? tv_b
                        : (y == 3) ? tqs_b : (y == 4) ? tks_b : tvs_b;
    const int n = (y < 3) ? TC : TS;   // both divisible by 4
    int i = th * 4;
    if (i < n) {
      float4 v = *(const float4*)(in + i);
      ushort4 o;
      o.x = f2bf(v.x); o.y = f2bf(v.y); o.z = f2bf(v.z); o.w = f2bf(v.w);
      *(ushort4*)(out + i) = o;
    }
  } else {
    // ---- edge binning: one thread per (branch, node, edge) ----------------
#pragma clang fp contract(off)
    const int t2  = (bid - PB3) * 256 + tid;     // < 2*NP*16 exactly
    const int b   = t2 / (NP * 16);
    const int rem = t2 - b * NP * 16;
    const int n   = rem >> 4;
    const int e   = rem & 15;
    int4 o;
    if (b == 0) {
      const int i1 = nb_c[n * 16 + e];
      const float rel[3] = {xyz[n * 3 + 0] - xyz[i1 * 3 + 0],
                            xyz[n * 3 + 1] - xyz[i1 * 3 + 1],
                            xyz[n * 3 + 2] - xyz[i1 * 3 + 2]};
      int r[3];
      #pragma unroll
      for (int dim = 0; dim < 3; ++dim) {
        int idx = (int)floorf(rel[dim] * 4.0f) + 23;
        idx = min(max(idx, 0), 46);
        r[dim] = idx * 3 + dim;
      }
      o.x = r[0]; o.y = r[1]; o.z = r[2]; o.w = i1;
    } else {
      const int i1 = nb_s[n * 16 + e];
      const float PIF = 3.14159265358979323846f;
      const float R2D = 57.29577951308232f;
      float xn = xyz[n * 3 + 0], yn = xyz[n * 3 + 1], zn = xyz[n * 3 + 2];
      float sxyn = xn * xn + yn * yn;
      const float tn0 = (f32_atan2(yn, xn) + PIF) * R2D;
      const float tn1 = f32_atan2(sqrtf(sxyn), zn) * R2D;
      const float tn2 = sqrtf(sxyn + zn * zn);
      float xm = xyz[i1 * 3 + 0], ym = xyz[i1 * 3 + 1], zm = xyz[i1 * 3 + 2];
      float sxym = xm * xm + ym * ym;
      const float tm0 = (f32_atan2(ym, xm) + PIF) * R2D;
      const float tm1 = f32_atan2(sqrtf(sxym), zm) * R2D;
      const float tm2 = sqrtf(sxym + zm * zm);
      const float d0 = tn0 - tm0;
      const float d1 = tn1 - tm1;
      const float dr = tn2 - tm2;
      int i0a = (int)floorf(d0 / 5.0f) + 24;
      int i1a = (int)floorf(d1 / 5.0f) + 24;
      const float ra = fabsf(dr);
      const float flag = (dr >= 0.0f) ? 1.0f : 0.0f;
      const float tt = (ra + 0.025f) / 0.0125f;
      const float wv = f32_log(tt) / 0.69314718055994531f;
      float fidx = 2.0f * floorf(wv) - 2.0f;
      fidx += ((3.0f * exp2f(floorf(fidx * 0.5f)) - 2.0f) * 0.0125f <= ra) ? 1.0f : 0.0f;
      fidx = fidx * (2.0f * flag - 1.0f) + (flag - 1.0f);
      int i2a = (int)fidx + 24;
      o.x = min(max(i0a, 0), 47) * 3 + 0;
      o.y = min(max(i1a, 0), 47) * 3 + 1;
      o.z = min(max(i2a, 0), 47) * 3 + 2;
      o.w = i1;
    }
    ebuf[t2] = o;
  }
}

// ------- bf16 MFMA GEMM, 256x128 tile, 8 waves (gemm0) ----------------------
// R16: doubles MFMA per barrier-pair (128 vs 64) and halves staging loads
// per MFMA (A-panel reuse x2) vs the 128^2 tile. 3-buffer depth-2 ledger:
// per wave 3 loads/stage (2A + 1B); top of iter t outstanding = {t,t+1} = 6;
// vmcnt(3) drains exactly tile t. LDS 72KB -> 2 blocks/CU. Staging overreads
// <= row 20223 (~172KB into qkv_b, valid); C stores guarded.
__global__ __launch_bounds__(512) void gemm256_k(const short* __restrict__ A,
                                                 const short* __restrict__ BT,
                                                 const float* __restrict__ bias,
                                                 unsigned short* __restrict__ Cout,
                                                 int M, int Nn, int K) {
  __shared__ short As[3][256][32];
  __shared__ short Bs[3][128][32];
  const int tid  = threadIdx.x;

  // bijective XCD chunk remap (m204)
  const int NT  = Nn >> 7;
  const int nwg = gridDim.x;
  const int q = nwg >> 3, r = nwg & 7;
  const int xcd = blockIdx.x & 7, j = blockIdx.x >> 3;
  const int wg = (xcd < r ? xcd * (q + 1) : r * (q + 1) + (xcd - r) * q) + j;
  const int m0 = (wg / NT) * 256, n0 = (wg % NT) * 128;

  const int wave = tid >> 6, lane = tid & 63;       // wave 0..7
  const int wm   = (wave & 3) * 64, wn = (wave >> 2) * 64;
  const int quad = lane >> 4, l16 = lane & 15;
  const int srow = lane >> 2;
  const int scol = (lane & 3) * 8;   // shorts

  f32x4 acc[4][4] = {};

  auto stage = [&](int buf, int k0) {
    #pragma unroll
    for (int c = 0; c < 2; ++c) {
      const int abase = (wave * 2 + c) * 16;       // 0..240, wave-uniform
      async16(A + (size_t)(m0 + abase + srow) * K + k0 + scol, &As[buf][abase][0]);
    }
    const int bbase = wave * 16;                    // 0..112
    async16(BT + (size_t)(n0 + bbase + srow) * K + k0 + scol, &Bs[buf][bbase][0]);
  };

  const int nt = K >> 5;          // 12
  stage(0, 0);
  stage(1, 32);
  for (int t = 0; t < nt; ++t) {
    const int cur = t % 3;
    if (t + 1 < nt) {
      asm volatile("s_waitcnt vmcnt(3)" ::: "memory");   // tile t landed
    } else {
      asm volatile("s_waitcnt vmcnt(0)" ::: "memory");
    }
    __builtin_amdgcn_s_barrier();
    short8 af[4], bg[4];
    #pragma unroll
    for (int i = 0; i < 4; ++i) af[i] = *(const short8*)&As[cur][wm + i * 16 + l16][quad * 8];
    #pragma unroll
    for (int j2 = 0; j2 < 4; ++j2) bg[j2] = *(const short8*)&Bs[cur][wn + j2 * 16 + l16][quad * 8];
    #pragma unroll
    for (int i = 0; i < 4; ++i)
      #pragma unroll
      for (int j2 = 0; j2 < 4; ++j2)
        acc[i][j2] = __builtin_amdgcn_mfma_f32_16x16x32_bf16(af[i], bg[j2], acc[i][j2], 0, 0, 0);
    __builtin_amdgcn_s_barrier();
    if (t + 2 < nt) stage((t + 2) % 3, (t + 2) * 32);
  }

  #pragma unroll
  for (int i = 0; i < 4; ++i) {
    #pragma unroll
    for (int r2 = 0; r2 < 4; ++r2) {
      const int gm = m0 + wm + i * 16 + quad * 4 + r2;
      if (gm >= M) continue;
      #pragma unroll
      for (int j2 = 0; j2 < 4; ++j2) {
        const int gn = n0 + wn + j2 * 16 + l16;
        float v = acc[i][j2][r2] + bias[gn];
        if (gn < 384) v *= 0.125f;   // SCALE = 64^-0.5 (q columns)
        Cout[(size_t)gm * Nn + gn] = f2bf(v);
      }
    }
  }
}

// ------- bf16 MFMA GEMM, 128x128 tile (R9 version; used for gemm1) ----------
// Ledger: per wave 4 loads/stage; vmcnt(4); 3 buffers. fp32 out.
__global__ __launch_bounds__(256) void gemm_async_k(const short* __restrict__ A,
                                                    const short* __restrict__ BT,
                                                    const float* __restrict__ bias,
                                                    float* __restrict__ Cout,
                                                    int M, int Nn, int K) {
  __shared__ short As[3][128][32];
  __shared__ short Bs[3][128][32];
  const int tid  = threadIdx.x;

  const int NT  = Nn >> 7;
  const int nwg = gridDim.x;
  const int q = nwg >> 3, r = nwg & 7;
  const int xcd = blockIdx.x & 7, j = blockIdx.x >> 3;
  const int wg = (xcd < r ? xcd * (q + 1) : r * (q + 1) + (xcd - r) * q) + j;
  const int m0 = (wg / NT) * 128, n0 = (wg % NT) * 128;

  const int wave = tid >> 6, lane = tid & 63;
  const int wm   = (wave & 1) * 64, wn = (wave >> 1) * 64;
  const int quad = lane >> 4, l16 = lane & 15;
  const int srow = lane >> 2;
  const int scol = (lane & 3) * 8;   // shorts

  f32x4 acc[4][4] = {};

  auto stage = [&](int buf, int k0) {
    #pragma unroll
    for (int c = 0; c < 2; ++c) {
      const int base = (wave + c * 4) * 16;      // wave-uniform: 0..112
      async16(A + (size_t)(m0 + base + srow) * K + k0 + scol, &As[buf][base][0]);
      async16(BT + (size_t)(n0 + base + srow) * K + k0 + scol, &Bs[buf][base][0]);
    }
  };

  const int nt = K >> 5;
  stage(0, 0);
  stage(1, 32);
  for (int t = 0; t < nt; ++t) {
    const int cur = t % 3;
    if (t + 1 < nt) {
      asm volatile("s_waitcnt vmcnt(4)" ::: "memory");
    } else {
      asm volatile("s_waitcnt vmcnt(0)" ::: "memory");
    }
    __builtin_amdgcn_s_barrier();
    short8 af[4], bg[4];
    #pragma unroll
    for (int i = 0; i < 4; ++i) af[i] = *(const short8*)&As[cur][wm + i * 16 + l16][quad * 8];
    #pragma unroll
    for (int j2 = 0; j2 < 4; ++j2) bg[j2] = *(const short8*)&Bs[cur][wn + j2 * 16 + l16][quad * 8];
    #pragma unroll
    for (int i = 0; i < 4; ++i)
      #pragma unroll
      for (int j2 = 0; j2 < 4; ++j2)
        acc[i][j2] = __builtin_amdgcn_mfma_f32_16x16x32_bf16(af[i], bg[j2], acc[i][j2], 0, 0, 0);
    __builtin_amdgcn_s_barrier();
    if (t + 2 < nt) stage((t + 2) % 3, (t + 2) * 32);
  }

  #pragma unroll
  for (int i = 0; i < 4; ++i) {
    #pragma unroll
    for (int r2 = 0; r2 < 4; ++r2) {
      const int gm = m0 + wm + i * 16 + quad * 4 + r2;
      if (gm >= M) continue;
      #pragma unroll
      for (int j2 = 0; j2 < 4; ++j2) {
        const int gn = n0 + wn + j2 * 16 + l16;
        if (gn >= Nn) continue;
        Cout[(size_t)gm * Nn + gn] = acc[i][j2][r2] + bias[gn];
      }
    }
  }
}

// 8-dim partial, packed f32 math (fallback when no HW bf16 dot).
__device__ inline f32x2 dot8_pk(uint4 q, uint4 k, uint4 a0, uint4 a1, uint4 a2,
                                uint4 t0, uint4 t1, uint4 t2, f32x2 acc) {
  const unsigned* qp = &q.x;  const unsigned* kp = &k.x;
  const unsigned* a0p = &a0.x; const unsigned* a1p = &a1.x; const unsigned* a2p = &a2.x;
  const unsigned* t0p = &t0.x; const unsigned* t1p = &t1.x; const unsigned* t2p = &t2.x;
  #pragma unroll
  for (int w2 = 0; w2 < 4; ++w2) {
    f32x2 qf = up2(qp[w2]), kf = up2(kp[w2]);
    f32x2 tqs = up2(a0p[w2]) + up2(a1p[w2]) + up2(a2p[w2]);
    f32x2 tks = up2(t0p[w2]) + up2(t1p[w2]) + up2(t2p[w2]);
    acc += qf * (kf + tqs) + kf * tks;
  }
  return acc;
}

// V-phase accumulate: vc[0..3] += pr * (vv + t0 + t1 + t2), per-dword packed.
__device__ inline void acc4(f32x2* vc, uint4 vv, uint4 t0, uint4 t1, uint4 t2,
                            float pr) {
  f32x2 prv = {pr, pr};
  vc[0] += prv * (up2(vv.x) + up2(t0.x) + up2(t1.x) + up2(t2.x));
  vc[1] += prv * (up2(vv.y) + up2(t0.y) + up2(t1.y) + up2(t2.y));
  vc[2] += prv * (up2(vv.z) + up2(t0.z) + up2(t1.z) + up2(t2.z));
  vc[3] += prv * (up2(vv.w) + up2(t0.w) + up2(t1.w) + up2(t2.w));
}

// -------- fused sparse attention, LDS-staged tables, 16-wave blocks ---------
// R11 config verbatim (best measured: 108.5us, single dispatch).
__global__ __launch_bounds__(1024, 4) void attn_lds_k(const unsigned short* __restrict__ qkv,
                                                      const int4* __restrict__ ebuf,
                                                      const unsigned short* __restrict__ tq_c,
                                                      const unsigned short* __restrict__ tk_c,
                                                      const unsigned short* __restrict__ tv_c,
                                                      const unsigned short* __restrict__ tq_s,
                                                      const unsigned short* __restrict__ tk_s,
                                                      const unsigned short* __restrict__ tv_s,
                                                      unsigned short* __restrict__ xout) {
  __shared__ char s_tq[144 * 128];
  __shared__ char s_tk[144 * 128];
  __shared__ char s_tv[144 * 128];

  const int bh  = blockIdx.x;      // 0..5
  const int b   = bh / 3;          // branch
  const int hh  = bh % 3;          // head within branch
  const int wid = threadIdx.x >> 6, lane = threadIdx.x & 63;

  const unsigned short* gtq = b ? tq_s : tq_c;
  const unsigned short* gtk = b ? tk_s : tk_c;
  const unsigned short* gtv = b ? tv_s : tv_c;
  const int nrows = b ? 144 : 141;

  // ---- stage table head-slices into LDS (row = r*3+d, 128B rows) ----------
  for (int i = threadIdx.x; i < nrows * 8; i += 1024) {
    const int row = i >> 3, c8 = i & 7;
    const int go = row * 192 + hh * 64 + c8 * 8;   // global elem offset
    tst(s_tq, row, c8 * 16, *(const uint4*)(gtq + go));
    tst(s_tk, row, c8 * 16, *(const uint4*)(gtk + go));
    tst(s_tv, row, c8 * 16, *(const uint4*)(gtv + go));
  }
  __syncthreads();

  const int eg = lane >> 2, g = lane & 3;       // logits mapping
  const int e8 = lane >> 3, c = lane & 7;       // V mapping
  const int node_end = min(blockIdx.y * ANB + ANB, NP);

  for (int node = blockIdx.y * ANB + wid; node < node_end; node += 16) {
    const int4* eb = ebuf + ((size_t)b * NP + node) * 16;

    // per-lane index loads (coalesced 4/8-dup within 256B)
    const int4 E  = eb[eg];                     // logits edge
    const int4 EA = eb[e8];                     // V edges
    const int4 EB = eb[e8 + 8];

    // q + k + v global loads issued up front (v flies under logits+softmax)
    const unsigned short* qp = qkv + (size_t)node * QKVD + b * 192 + hh * 64 + g * 16;
    const uint4 qv0 = *(const uint4*)(qp);
    const uint4 qv1 = *(const uint4*)(qp + 8);
    const unsigned short* kp = qkv + (size_t)E.w * QKVD + 384 + b * 192 + hh * 64 + g * 16;
    const uint4 kv0 = *(const uint4*)(kp);
    const uint4 kv1 = *(const uint4*)(kp + 8);
    const int hc = hh * 64 + c * 8;
    const uint4 vA = *(const uint4*)(qkv + (size_t)EA.w * QKVD + 768 + b * 192 + hc);
    const uint4 vB = *(const uint4*)(qkv + (size_t)EB.w * QKVD + 768 + b * 192 + hc);

    // table operands from LDS (swizzled)
    const int bo = g * 32;
    const uint4 a00 = tld(s_tq, E.x, bo), a01 = tld(s_tq, E.x, bo + 16);
    const uint4 a10 = tld(s_tq, E.y, bo), a11 = tld(s_tq, E.y, bo + 16);
    const uint4 a20 = tld(s_tq, E.z, bo), a21 = tld(s_tq, E.z, bo + 16);
    const uint4 b00 = tld(s_tk, E.x, bo), b01 = tld(s_tk, E.x, bo + 16);
    const uint4 b10 = tld(s_tk, E.y, bo), b11 = tld(s_tk, E.y, bo + 16);
    const uint4 b20 = tld(s_tk, E.z, bo), b21 = tld(s_tk, E.z, bo + 16);

    float acc;
#ifdef HAVE_BF16_DOT
    float aqk = 0.0f, aq0 = 0.0f, aq1 = 0.0f, aq2 = 0.0f;
    float ak0 = 0.0f, ak1 = 0.0f, ak2 = 0.0f;
#define DOT7(qd, kd, a0d, a1d, a2d, b0d, b1d, b2d)                         \
    aqk = dot2bf(qd, kd, aqk);  aq0 = dot2bf(qd, a0d, aq0);                \
    aq1 = dot2bf(qd, a1d, aq1); aq2 = dot2bf(qd, a2d, aq2);                \
    ak0 = dot2bf(kd, b0d, ak0); ak1 = dot2bf(kd, b1d, ak1);                \
    ak2 = dot2bf(kd, b2d, ak2);
    DOT7(qv0.x, kv0.x, a00.x, a10.x, a20.x, b00.x, b10.x, b20.x)
    DOT7(qv0.y, kv0.y, a00.y, a10.y, a20.y, b00.y, b10.y, b20.y)
    DOT7(qv0.z, kv0.z, a00.z, a10.z, a20.z, b00.z, b10.z, b20.z)
    DOT7(qv0.w, kv0.w, a00.w, a10.w, a20.w, b00.w, b10.w, b20.w)
    DOT7(qv1.x, kv1.x, a01.x, a11.x, a21.x, b01.x, b11.x, b21.x)
    DOT7(qv1.y, kv1.y, a01.y, a11.y, a21.y, b01.y, b11.y, b21.y)
    DOT7(qv1.z, kv1.z, a01.z, a11.z, a21.z, b01.z, b11.z, b21.z)
    DOT7(qv1.w, kv1.w, a01.w, a11.w, a21.w, b01.w, b11.w, b21.w)
#undef DOT7
    acc = ((aqk + aq0) + (aq1 + aq2)) + ((ak0 + ak1) + ak2);
#else
    f32x2 acc2 = {0.0f, 0.0f};
    acc2 = dot8_pk(qv0, kv0, a00, a10, a20, b00, b10, b20, acc2);
    acc2 = dot8_pk(qv1, kv1, a01, a11, a21, b01, b11, b21, acc2);
    acc = acc2.x + acc2.y;
#endif
    // edge-local reduce over 4 dim-groups (lane bits 0..1)
    acc += __shfl_xor(acc, 1);
    acc += __shfl_xor(acc, 2);

    // in-wave softmax over 16 edges (lane bits 2..5)
    float m = acc;
    #pragma unroll
    for (int off = 4; off <= 32; off <<= 1) m = fmaxf(m, __shfl_xor(m, off));
    float ex = __expf(acc - m);
    float s = ex;
    #pragma unroll
    for (int off = 4; off <= 32; off <<= 1) s += __shfl_xor(s, off);
    const float p = ex / s;

    // V phase: p for edges e8 / e8+8 via shuffle from lane 4*e
    const float pA = __shfl(p, e8 << 2);
    const float pB = __shfl(p, (e8 + 8) << 2);
    const int vbo = c * 16;
    const uint4 tA0 = tld(s_tv, EA.x, vbo);
    const uint4 tA1 = tld(s_tv, EA.y, vbo);
    const uint4 tA2 = tld(s_tv, EA.z, vbo);
    const uint4 tB0 = tld(s_tv, EB.x, vbo);
    const uint4 tB1 = tld(s_tv, EB.y, vbo);
    const uint4 tB2 = tld(s_tv, EB.z, vbo);

    f32x2 vc[4] = {{0.f, 0.f}, {0.f, 0.f}, {0.f, 0.f}, {0.f, 0.f}};
    acc4(vc, vA, tA0, tA1, tA2, pA);
    acc4(vc, vB, tB0, tB1, tB2, pB);

    #pragma unroll
    for (int q4 = 0; q4 < 4; ++q4) {
      #pragma unroll
      for (int off = 8; off <= 32; off <<= 1) {
        vc[q4].x += __shfl_xor(vc[q4].x, off);
        vc[q4].y += __shfl_xor(vc[q4].y, off);
      }
    }
    if (e8 == 0) {
      uint4 o;
      o.x = ((unsigned)f2bf(vc[0].y) << 16) | (unsigned)f2bf(vc[0].x);
      o.y = ((unsigned)f2bf(vc[1].y) << 16) | (unsigned)f2bf(vc[1].x);
      o.z = ((unsigned)f2bf(vc[2].y) << 16) | (unsigned)f2bf(vc[2].x);
      o.w = ((unsigned)f2bf(vc[3].y) << 16) | (unsigned)f2bf(vc[3].x);
      *(uint4*)(xout + (size_t)node * CD + (b * 3 + hh) * 64 + c * 8) = o;
    }
  }
}

}  // namespace

extern "C" void kernel_launch(void* const* d_in, const int* in_sizes, int n_in,
                              void* d_out, int out_size, void* d_ws, size_t ws_size,
                              hipStream_t stream) {
  const float* qf    = (const float*)d_in[0];
  const float* xyz   = (const float*)d_in[1];
  const int*   i1c   = (const int*)d_in[3];   // index_1
  const int*   i1s   = (const int*)d_in[5];   // index_1_sphere
  const float* Wqkv  = (const float*)d_in[6];
  const float* bqkv  = (const float*)d_in[7];
  const float* Wproj = (const float*)d_in[8];
  const float* bproj = (const float*)d_in[9];
  const float* tq    = (const float*)d_in[10];
  const float* tk    = (const float*)d_in[11];
  const float* tv    = (const float*)d_in[12];
  const float* tqs   = (const float*)d_in[13];
  const float* tks   = (const float*)d_in[14];
  const float* tvs   = (const float*)d_in[15];

  char* w = (char*)d_ws;
  unsigned short* qf_b   = (unsigned short*)w; w += (size_t)NP * CD * 2;    // 15.36 MB
  unsigned short* wqkvT  = (unsigned short*)w; w += (size_t)QKVD * CD * 2;  // 0.88 MB
  unsigned short* wprojT = (unsigned short*)w; w += (size_t)CD * CD * 2;    // 0.29 MB
  unsigned short* qkv_b  = (unsigned short*)w; w += (size_t)NP * QKVD * 2;  // 46.08 MB
  unsigned short* x_b    = (unsigned short*)w; w += (size_t)NP * CD * 2;    // 15.36 MB
  unsigned short* tq_b   = (unsigned short*)w; w += (size_t)TC * 2;
  unsigned short* tk_b   = (unsigned short*)w; w += (size_t)TC * 2;
  unsigned short* tv_b   = (unsigned short*)w; w += (size_t)TC * 2;
  unsigned short* tqs_b  = (unsigned short*)w; w += (size_t)TS * 2;
  unsigned short* tks_b  = (unsigned short*)w; w += (size_t)TS * 2;
  unsigned short* tvs_b  = (unsigned short*)w; w += (size_t)TS * 2;
  int4*           ebuf   = (int4*)w;           // 10.24 MB

  prep_all_k<<<PB4, 256, 0, stream>>>(qf, qf_b, Wqkv, wqkvT, Wproj, wprojT,
                                      tq, tk, tv, tqs, tks, tvs,
                                      tq_b, tk_b, tv_b, tqs_b, tks_b, tvs_b,
                                      xyz, i1c, i1s, ebuf);

  gemm256_k<<<((NP + 255) / 256) * (QKVD / 128), 512, 0, stream>>>(
      (const short*)qf_b, (const short*)wqkvT, bqkv, qkv_b, NP, QKVD, CD);

  attn_lds_k<<<dim3(6, ANY), 1024, 0, stream>>>(qkv_b, ebuf,
                                                tq_b, tk_b, tv_b,
                                                tqs_b, tks_b, tvs_b, x_b);

  gemm_async_k<<<((NP + 127) / 128) * (CD / 128), 256, 0, stream>>>(
      (const short*)x_b, (const short*)wprojT, bproj, (float*)d_out, NP, CD, CD);
}